// Round 3
// baseline (716.569 us; speedup 1.0000x reference)
//
#include <hip/hip_runtime.h>
#include <hip/hip_bf16.h>
#include <math.h>

#define N_NODES 4096
#define DIM_IN  512
#define DH1     256
#define DH2     64
#define ALPHA   0.2f
#define ROW_WORDS (N_NODES / 64)              // 64 uint64 per row
#define NWORDS  (N_NODES * ROW_WORDS)         // 262144

typedef __bf16 bf16_t;
typedef bf16_t bf16x8 __attribute__((ext_vector_type(8)));
typedef float  f32x4  __attribute__((ext_vector_type(4)));

// ---------------------------------------------------------------- fp32 -> bf16 convert (n % 4 == 0)
__global__ __launch_bounds__(256) void cvt_kernel(
    const float* __restrict__ in, bf16_t* __restrict__ out, int n4)
{
    int i = blockIdx.x * 256 + threadIdx.x;
    if (i < n4) {
        float4 v = ((const float4*)in)[i];
        bf16_t o[4] = {(bf16_t)v.x, (bf16_t)v.y, (bf16_t)v.z, (bf16_t)v.w};
        *(uint2*)(out + (size_t)i * 4) = *(const uint2*)o;
    }
}

// ---------------------------------------------------------------- pack adj -> bitmask
__global__ __launch_bounds__(256) void pack_mask_kernel(
    const int* __restrict__ adj, unsigned long long* __restrict__ mask)
{
    const int lane = threadIdx.x & 63;
    int gw = (blockIdx.x * 256 + threadIdx.x) >> 6;
    const int nw = (gridDim.x * 256) >> 6;
    for (int w = gw; w < NWORDS; w += nw) {
        int v = adj[(size_t)w * 64 + lane];
        unsigned long long b = __ballot(v > 0);
        if (lane == 0) mask[w] = b;
    }
}

// ---------------------------------------------------------------- f1/f2 = h @ a[:d], h @ a[d:]  (h bf16, a fp32)
__global__ __launch_bounds__(256) void f1f2_kernel(
    const bf16_t* __restrict__ h, const float* __restrict__ a,
    float* __restrict__ f1, float* __restrict__ f2, int d)
{
    const int wave = threadIdx.x >> 6, lane = threadIdx.x & 63;
    const int row = blockIdx.x * 4 + wave;
    const bf16_t* hr = h + (size_t)row * d;
    float s1 = 0.f, s2 = 0.f;
    for (int c = lane; c < d; c += 64) {
        float hv = (float)hr[c];
        s1 += hv * a[c];
        s2 += hv * a[d + c];
    }
    for (int off = 32; off; off >>= 1) {
        s1 += __shfl_down(s1, off);
        s2 += __shfl_down(s2, off);
    }
    if (lane == 0) { f1[row] = s1; f2[row] = s2; }
}

// ---------------------------------------------------------------- per-row softmax stats (max, sum)
__global__ __launch_bounds__(256) void rowstats_kernel(
    const unsigned long long* __restrict__ mask,
    const float* __restrict__ f1, const float* __restrict__ f2,
    float* __restrict__ mrow, float* __restrict__ srow)
{
    __shared__ float f2s[N_NODES];
    const int tid = threadIdx.x;
    for (int j = tid; j < N_NODES; j += 256) f2s[j] = f2[j];
    __syncthreads();
    const int wave = tid >> 6, lane = tid & 63;
    const int row = blockIdx.x * 4 + wave;
    const float fi = f1[row];
    const unsigned long long* mw = mask + (size_t)row * ROW_WORDS;

    float mx = -3.0e38f;
    for (int t = 0; t < ROW_WORDS; ++t) {
        unsigned long long w = mw[t];
        if ((w >> lane) & 1ull) {
            float e = fi + f2s[t * 64 + lane];
            e = e > 0.f ? e : ALPHA * e;
            mx = fmaxf(mx, e);
        }
    }
    for (int off = 32; off; off >>= 1) mx = fmaxf(mx, __shfl_xor(mx, off));

    float sum = 0.f;
    if (mx > -2.0e38f) {
        for (int t = 0; t < ROW_WORDS; ++t) {
            unsigned long long w = mw[t];
            if ((w >> lane) & 1ull) {
                float e = fi + f2s[t * 64 + lane];
                e = e > 0.f ? e : ALPHA * e;
                sum += __expf(e - mx);
            }
        }
    }
    for (int off = 32; off; off >>= 1) sum += __shfl_xor(sum, off);
    if (lane == 0) {
        if (mx > -2.0e38f) { mrow[row] = mx; srow[row] = sum; }
        else               { mrow[row] = 0.f; srow[row] = 0.f; }  // all-masked row -> uniform
    }
}

// ---------------------------------------------------------------- materialize P (bf16 attention probs)
__global__ __launch_bounds__(256) void genP_kernel(
    const unsigned long long* __restrict__ mask,
    const float* __restrict__ f1, const float* __restrict__ f2,
    const float* __restrict__ mrow, const float* __restrict__ srow,
    bf16_t* __restrict__ P)
{
    const int lane = threadIdx.x & 63;
    int gw = (blockIdx.x * 256 + threadIdx.x) >> 6;
    const int nw = (gridDim.x * 256) >> 6;
    for (int w = gw; w < NWORDS; w += nw) {
        const int row = w >> 6, t = w & 63;
        unsigned long long wd = mask[w];
        float fi = f1[row], m = mrow[row], s = srow[row];
        float rs = (s > 0.f) ? 1.f / s : 0.f;
        int j = t * 64 + lane;
        float p;
        if (s <= 0.f) {
            p = 1.0f / (float)N_NODES;         // reference: softmax of all -9e15 = uniform
        } else if ((wd >> lane) & 1ull) {
            float e = fi + f2[j];
            e = e > 0.f ? e : ALPHA * e;
            p = __expf(e - m) * rs;
        } else {
            p = 0.f;
        }
        P[(size_t)row * N_NODES + j] = (bf16_t)p;
    }
}

// ---------------------------------------------------------------- generic bf16 GEMM: C[M,N] = A[M,K] @ B[K,N]
// A,B row-major bf16, fp32 accumulate. EP: 0 = plain store, 1 = sigmoid store. CT: output type.
// block = 256 thr (4 waves); block tile 64x64; wave w -> rows [w*16,w*16+16), all 64 cols.
template <int EP, typename CT>
__global__ __launch_bounds__(256) void gemm_bf16_kernel(
    const bf16_t* __restrict__ A, const bf16_t* __restrict__ B,
    CT* __restrict__ C, int M, int N, int K)
{
    __shared__ bf16_t BT[64][40];   // BT[n][k] for current 32-k slab
    const int tid  = threadIdx.x;
    const int wave = tid >> 6;
    const int lane = tid & 63;
    const int quad = lane >> 4;
    const int l16  = lane & 15;
    const int colBase = blockIdx.x * 64;
    const int rowBase = blockIdx.y * 64;
    const int m = rowBase + wave * 16 + l16;      // A row this lane reads

    const int sr = tid >> 3;           // staging: k row 0..31
    const int sc = (tid & 7) * 8;      // staging: col base within tile

    f32x4 acc[4] = {};

    for (int k0 = 0; k0 < K; k0 += 32) {
        {   // stage B[k0..k0+32) x [colBase..colBase+64) transposed into BT
            const bf16_t* bp = B + (size_t)(k0 + sr) * N + colBase + sc;
            bf16x8 bv = *(const bf16x8*)bp;
            #pragma unroll
            for (int i = 0; i < 8; ++i) BT[sc + i][sr] = bv[i];
        }
        __syncthreads();
        bf16x8 av = *(const bf16x8*)(A + (size_t)m * K + k0 + quad * 8);
        #pragma unroll
        for (int t = 0; t < 4; ++t) {
            bf16x8 bv = *(const bf16x8*)(&BT[t * 16 + l16][quad * 8]);
            acc[t] = __builtin_amdgcn_mfma_f32_16x16x32_bf16(av, bv, acc[t], 0, 0, 0);
        }
        __syncthreads();
    }

    #pragma unroll
    for (int t = 0; t < 4; ++t) {
        #pragma unroll
        for (int r = 0; r < 4; ++r) {
            float v = acc[t][r];
            if (EP == 1) v = 1.0f / (1.0f + __expf(-v));
            const int row = rowBase + wave * 16 + quad * 4 + r;
            const int col = colBase + t * 16 + l16;
            C[(size_t)row * N + col] = (CT)v;
        }
    }
}

// ---------------------------------------------------------------- Z = noise*exp(logstd)+mean (fp32),
// then split Z = Zhi + Zlo (bf16 pair) and lay out for the K=256 exact GEMM:
//   ZA rows: [hi | hi | lo | lo], ZB rows (transposed): [hi ; lo ; hi ; lo]
// so sum_k ZA[i,k]*ZB[k,j] = (hi_i+lo_i)·(hi_j+lo_j)  (fp32-accurate Z@Z^T)
__global__ __launch_bounds__(256) void z_split_kernel(
    const float* __restrict__ noise, const float* __restrict__ mean,
    const float* __restrict__ logstd,
    bf16_t* __restrict__ ZA, bf16_t* __restrict__ ZB)
{
    const int idx = blockIdx.x * 256 + threadIdx.x;  // < N*DH2
    const int i = idx >> 6, c = idx & 63;
    float z = noise[idx] * __expf(logstd[idx]) + mean[idx];
    bf16_t zhi = (bf16_t)z;
    bf16_t zlo = (bf16_t)(z - (float)zhi);
    const size_t rb = (size_t)i * 256;
    ZA[rb + c]       = zhi;
    ZA[rb + 64 + c]  = zhi;
    ZA[rb + 128 + c] = zlo;
    ZA[rb + 192 + c] = zlo;
    ZB[(size_t)c * N_NODES + i]         = zhi;
    ZB[(size_t)(64 + c) * N_NODES + i]  = zlo;
    ZB[(size_t)(128 + c) * N_NODES + i] = zhi;
    ZB[(size_t)(192 + c) * N_NODES + i] = zlo;
}

// ================================================================ launch
extern "C" void kernel_launch(void* const* d_in, const int* in_sizes, int n_in,
                              void* d_out, int out_size, void* d_ws, size_t ws_size,
                              hipStream_t stream)
{
    const float* X     = (const float*)d_in[0];
    const int*   adj   = (const int*)  d_in[1];
    const float* noise = (const float*)d_in[2];
    const float* W0    = (const float*)d_in[3];
    const float* a0    = (const float*)d_in[4];
    const float* W1    = (const float*)d_in[5];
    const float* a1    = (const float*)d_in[6];
    const float* W2    = (const float*)d_in[7];
    const float* a2    = (const float*)d_in[8];
    float* out = (float*)d_out;

    char* ws = (char*)d_ws;
    size_t off = 0;
    auto alloc = [&](size_t bytes) { char* p = ws + off; off += (bytes + 255) & ~(size_t)255; return p; };

    unsigned long long* mask = (unsigned long long*)alloc((size_t)NWORDS * 8);        // 2 MB
    bf16_t* P       = (bf16_t*)alloc((size_t)N_NODES * N_NODES * 2);                  // 33.5 MB
    bf16_t* Xb      = (bf16_t*)alloc((size_t)N_NODES * DIM_IN * 2);                   // 4 MB
    bf16_t* W0b     = (bf16_t*)alloc((size_t)DIM_IN * DH1 * 2);
    bf16_t* W1b     = (bf16_t*)alloc((size_t)DH1 * DH2 * 2);
    bf16_t* W2b     = (bf16_t*)alloc((size_t)DH1 * DH2 * 2);
    bf16_t* h0      = (bf16_t*)alloc((size_t)N_NODES * DH1 * 2);                      // 2 MB
    bf16_t* hid     = (bf16_t*)alloc((size_t)N_NODES * DH1 * 2);                      // 2 MB
    bf16_t* h1      = (bf16_t*)alloc((size_t)N_NODES * DH2 * 2);
    bf16_t* h2      = (bf16_t*)alloc((size_t)N_NODES * DH2 * 2);
    float*  meanb   = (float*)alloc((size_t)N_NODES * DH2 * 4);                       // 1 MB fp32
    float*  logstdb = (float*)alloc((size_t)N_NODES * DH2 * 4);                       // 1 MB fp32
    bf16_t* ZA      = (bf16_t*)alloc((size_t)N_NODES * 4 * DH2 * 2);                  // 2 MB
    bf16_t* ZB      = (bf16_t*)alloc((size_t)N_NODES * 4 * DH2 * 2);                  // 2 MB
    float* f1   = (float*)alloc((size_t)N_NODES * 4);
    float* f2   = (float*)alloc((size_t)N_NODES * 4);
    float* mrow = (float*)alloc((size_t)N_NODES * 4);
    float* srow = (float*)alloc((size_t)N_NODES * 4);
    (void)ws_size; (void)in_sizes; (void)n_in; (void)out_size;

    dim3 blk(256);

    // fp32 -> bf16 conversions
    cvt_kernel<<<(N_NODES * DIM_IN / 4 + 255) / 256, blk, 0, stream>>>(X,  Xb,  N_NODES * DIM_IN / 4);
    cvt_kernel<<<(DIM_IN * DH1 / 4 + 255) / 256, blk, 0, stream>>>(W0, W0b, DIM_IN * DH1 / 4);
    cvt_kernel<<<(DH1 * DH2 / 4 + 255) / 256, blk, 0, stream>>>(W1, W1b, DH1 * DH2 / 4);
    cvt_kernel<<<(DH1 * DH2 / 4 + 255) / 256, blk, 0, stream>>>(W2, W2b, DH1 * DH2 / 4);

    // adj -> bitmask (read 67 MB once)
    pack_mask_kernel<<<2048, blk, 0, stream>>>(adj, mask);

    // ---- layer 0: hidden = softmax(mask(lrelu(f1+f2^T))) @ (X@W0)
    gemm_bf16_kernel<0><<<dim3(DH1 / 64, N_NODES / 64), blk, 0, stream>>>(Xb, W0b, h0, N_NODES, DH1, DIM_IN);
    f1f2_kernel<<<N_NODES / 4, blk, 0, stream>>>(h0, a0, f1, f2, DH1);
    rowstats_kernel<<<N_NODES / 4, blk, 0, stream>>>(mask, f1, f2, mrow, srow);
    genP_kernel<<<4096, blk, 0, stream>>>(mask, f1, f2, mrow, srow, P);
    gemm_bf16_kernel<0><<<dim3(DH1 / 64, N_NODES / 64), blk, 0, stream>>>(P, h0, hid, N_NODES, DH1, N_NODES);

    // ---- layer 1: mean (fp32 out)
    gemm_bf16_kernel<0><<<dim3(DH2 / 64, N_NODES / 64), blk, 0, stream>>>(hid, W1b, h1, N_NODES, DH2, DH1);
    f1f2_kernel<<<N_NODES / 4, blk, 0, stream>>>(h1, a1, f1, f2, DH2);
    rowstats_kernel<<<N_NODES / 4, blk, 0, stream>>>(mask, f1, f2, mrow, srow);
    genP_kernel<<<4096, blk, 0, stream>>>(mask, f1, f2, mrow, srow, P);
    gemm_bf16_kernel<0><<<dim3(DH2 / 64, N_NODES / 64), blk, 0, stream>>>(P, h1, meanb, N_NODES, DH2, N_NODES);

    // ---- layer 2: logstd (fp32 out)
    gemm_bf16_kernel<0><<<dim3(DH2 / 64, N_NODES / 64), blk, 0, stream>>>(hid, W2b, h2, N_NODES, DH2, DH1);
    f1f2_kernel<<<N_NODES / 4, blk, 0, stream>>>(h2, a2, f1, f2, DH2);
    rowstats_kernel<<<N_NODES / 4, blk, 0, stream>>>(mask, f1, f2, mrow, srow);
    genP_kernel<<<4096, blk, 0, stream>>>(mask, f1, f2, mrow, srow, P);
    gemm_bf16_kernel<0><<<dim3(DH2 / 64, N_NODES / 64), blk, 0, stream>>>(P, h2, logstdb, N_NODES, DH2, N_NODES);

    // ---- Z (fp32, hi/lo split) and A_pred = sigmoid(Z @ Z^T) via K=256 exact GEMM
    z_split_kernel<<<(N_NODES * DH2) / 256, blk, 0, stream>>>(noise, meanb, logstdb, ZA, ZB);
    gemm_bf16_kernel<1><<<dim3(N_NODES / 64, N_NODES / 64), blk, 0, stream>>>(ZA, ZB, out, N_NODES, N_NODES, 4 * DH2);
}

// Round 4
// 531.427 us; speedup vs baseline: 1.3484x; 1.3484x over previous
//
#include <hip/hip_runtime.h>
#include <hip/hip_bf16.h>
#include <math.h>

#define N_NODES 4096
#define DIM_IN  512
#define DH1     256
#define DH2     64
#define ALPHA   0.2f
#define ROW_WORDS (N_NODES / 64)
#define NWORDS  (N_NODES * ROW_WORDS)

typedef __bf16 bf16_t;
typedef bf16_t bf16x8 __attribute__((ext_vector_type(8)));
typedef float  f32x4  __attribute__((ext_vector_type(4)));

// ---------------------------------------------------------------- fp32 -> bf16 (straight)
__global__ __launch_bounds__(256) void cvt_kernel(
    const float* __restrict__ in, bf16_t* __restrict__ out, int n4)
{
    int i = blockIdx.x * 256 + threadIdx.x;
    if (i < n4) {
        float4 v = ((const float4*)in)[i];
        bf16_t o[4] = {(bf16_t)v.x, (bf16_t)v.y, (bf16_t)v.z, (bf16_t)v.w};
        *(uint2*)(out + (size_t)i * 4) = *(const uint2*)o;
    }
}

// ---------------------------------------------------------------- fp32 [K][N] -> bf16 [N][K] (transpose)
__global__ __launch_bounds__(256) void cvtT_kernel(
    const float* __restrict__ in, bf16_t* __restrict__ out, int Nn, int Kk)
{
    int o = blockIdx.x * 256 + threadIdx.x;
    if (o < Nn * Kk) {
        int n = o / Kk, k = o - n * Kk;
        out[o] = (bf16_t)in[(size_t)k * Nn + n];
    }
}

// ---------------------------------------------------------------- W12T[128][256]: rows 0..63 = W1^T, 64..127 = W2^T
__global__ __launch_bounds__(256) void w12t_kernel(
    const float* __restrict__ W1, const float* __restrict__ W2, bf16_t* __restrict__ out)
{
    int o = blockIdx.x * 256 + threadIdx.x;   // < 128*256
    int n = o >> 8, k = o & 255;
    const float* W = (n < 64) ? W1 : W2;
    out[o] = (bf16_t)W[(size_t)k * 64 + (n & 63)];
}

// ---------------------------------------------------------------- pack adj -> bitmask
__global__ __launch_bounds__(256) void pack_mask_kernel(
    const int* __restrict__ adj, unsigned long long* __restrict__ mask)
{
    const int lane = threadIdx.x & 63;
    int gw = (blockIdx.x * 256 + threadIdx.x) >> 6;
    const int nw = (gridDim.x * 256) >> 6;
    for (int w = gw; w < NWORDS; w += nw) {
        int v = adj[(size_t)w * 64 + lane];
        unsigned long long b = __ballot(v > 0);
        if (lane == 0) mask[w] = b;
    }
}

// ---------------------------------------------------------------- f1/f2 = h @ a[:d], h @ a[d:]
__global__ __launch_bounds__(256) void f1f2_kernel(
    const bf16_t* __restrict__ h, const float* __restrict__ a,
    float* __restrict__ f1, float* __restrict__ f2, int d, int ld)
{
    const int wave = threadIdx.x >> 6, lane = threadIdx.x & 63;
    const int row = blockIdx.x * 4 + wave;
    const bf16_t* hr = h + (size_t)row * ld;
    float s1 = 0.f, s2 = 0.f;
    for (int c = lane; c < d; c += 64) {
        float hv = (float)hr[c];
        s1 += hv * a[c];
        s2 += hv * a[d + c];
    }
    for (int off = 32; off; off >>= 1) {
        s1 += __shfl_down(s1, off);
        s2 += __shfl_down(s2, off);
    }
    if (lane == 0) { f1[row] = s1; f2[row] = s2; }
}

// ---------------------------------------------------------------- per-row softmax stats
__global__ __launch_bounds__(256) void rowstats_kernel(
    const unsigned long long* __restrict__ mask,
    const float* __restrict__ f1, const float* __restrict__ f2,
    float* __restrict__ mrow, float* __restrict__ srow)
{
    __shared__ float f2s[N_NODES];
    const int tid = threadIdx.x;
    for (int j = tid; j < N_NODES; j += 256) f2s[j] = f2[j];
    __syncthreads();
    const int wave = tid >> 6, lane = tid & 63;
    const int row = blockIdx.x * 4 + wave;
    const float fi = f1[row];
    const unsigned long long* mw = mask + (size_t)row * ROW_WORDS;

    float mx = -3.0e38f;
    for (int t = 0; t < ROW_WORDS; ++t) {
        unsigned long long w = mw[t];
        if ((w >> lane) & 1ull) {
            float e = fi + f2s[t * 64 + lane];
            e = e > 0.f ? e : ALPHA * e;
            mx = fmaxf(mx, e);
        }
    }
    for (int off = 32; off; off >>= 1) mx = fmaxf(mx, __shfl_xor(mx, off));

    float sum = 0.f;
    if (mx > -2.0e38f) {
        for (int t = 0; t < ROW_WORDS; ++t) {
            unsigned long long w = mw[t];
            if ((w >> lane) & 1ull) {
                float e = fi + f2s[t * 64 + lane];
                e = e > 0.f ? e : ALPHA * e;
                sum += __expf(e - mx);
            }
        }
    }
    for (int off = 32; off; off >>= 1) sum += __shfl_xor(sum, off);
    if (lane == 0) {
        if (mx > -2.0e38f) { mrow[row] = mx; srow[row] = sum; }
        else               { mrow[row] = 0.f; srow[row] = 0.f; }
    }
}

// ---------------------------------------------------------------- fused attention GEMM:
// out[row,col] += sum_k P(row,k) * hT[col][k], P generated in registers from (mask,f1,f2,m,s).
// grid: (N/64, 4096/64, KSPLIT). LDS-free; fp32 atomicAdd epilogue (out pre-zeroed).
template <int KLEN>
__global__ __launch_bounds__(256) void attn_fused_kernel(
    const unsigned long long* __restrict__ maskw,
    const float* __restrict__ f1, const float* __restrict__ f2,
    const float* __restrict__ mrow, const float* __restrict__ srow,
    const bf16_t* __restrict__ BT,   // [N][4096]
    float* __restrict__ outF, int N)
{
    const int tid = threadIdx.x;
    const int wave = tid >> 6, lane = tid & 63, quad = lane >> 4, l16 = lane & 15;
    const int colBase = blockIdx.x * 64;
    const int rowBase = blockIdx.y * 64;
    const int r = rowBase + wave * 16 + l16;      // P row this lane generates
    const float f1r = f1[r];
    const float m   = mrow[r];
    const float s   = srow[r];
    const float rs  = (s > 0.f) ? 1.f / s : 0.f;
    const bool  uni = (s <= 0.f);
    const unsigned long long* mw = maskw + (size_t)r * ROW_WORDS;

    f32x4 acc[4] = {};
    const int kBeg = blockIdx.z * KLEN;
    for (int k0 = kBeg; k0 < kBeg + KLEN; k0 += 32) {
        const int kc = k0 + quad * 8;
        unsigned bits = (unsigned)((mw[kc >> 6] >> (kc & 63)) & 0xFFull);
        float4 fa = *(const float4*)(f2 + kc);
        float4 fb = *(const float4*)(f2 + kc + 4);
        float ev[8] = {fa.x, fa.y, fa.z, fa.w, fb.x, fb.y, fb.z, fb.w};
        bf16x8 av;
        #pragma unroll
        for (int j = 0; j < 8; ++j) {
            float e = f1r + ev[j];
            e = fmaxf(e, ALPHA * e);
            float p = uni ? (1.0f / N_NODES)
                          : (((bits >> j) & 1u) ? __expf(e - m) * rs : 0.f);
            av[j] = (bf16_t)p;
        }
        #pragma unroll
        for (int t = 0; t < 4; ++t) {
            bf16x8 bv = *(const bf16x8*)(BT + (size_t)(colBase + t * 16 + l16) * N_NODES + kc);
            acc[t] = __builtin_amdgcn_mfma_f32_16x16x32_bf16(av, bv, acc[t], 0, 0, 0);
        }
    }
    #pragma unroll
    for (int t = 0; t < 4; ++t) {
        const int col = colBase + t * 16 + l16;
        #pragma unroll
        for (int rr = 0; rr < 4; ++rr) {
            const int row = rowBase + wave * 16 + quad * 4 + rr;
            atomicAdd(&outF[(size_t)row * N + col], acc[t][rr]);
        }
    }
}

// ---------------------------------------------------------------- LDS-free GEMM: C[M,N] = A[M,K] @ BT[N,K]^T
// EP: 1 = sigmoid. WT: 1 = also write bf16 transposed copy Ct[N][M].
template <int EP, int WT, typename CT>
__global__ __launch_bounds__(256) void gemm_bt_kernel(
    const bf16_t* __restrict__ A, const bf16_t* __restrict__ BT,
    CT* __restrict__ C, bf16_t* __restrict__ Ct, int M, int N, int K)
{
    const int tid = threadIdx.x;
    const int wave = tid >> 6, lane = tid & 63, quad = lane >> 4, l16 = lane & 15;
    const int colBase = blockIdx.x * 64, rowBase = blockIdx.y * 64;
    const int mr = rowBase + wave * 16 + l16;
    const bf16_t* Ap = A + (size_t)mr * K + quad * 8;

    f32x4 acc[4] = {};
    for (int k0 = 0; k0 < K; k0 += 32) {
        bf16x8 av = *(const bf16x8*)(Ap + k0);
        #pragma unroll
        for (int t = 0; t < 4; ++t) {
            bf16x8 bv = *(const bf16x8*)(BT + (size_t)(colBase + t * 16 + l16) * K + k0 + quad * 8);
            acc[t] = __builtin_amdgcn_mfma_f32_16x16x32_bf16(av, bv, acc[t], 0, 0, 0);
        }
    }
    #pragma unroll
    for (int t = 0; t < 4; ++t) {
        const int col = colBase + t * 16 + l16;
        bf16_t pk[4];
        #pragma unroll
        for (int rr = 0; rr < 4; ++rr) {
            float v = acc[t][rr];
            if (EP == 1) v = 1.0f / (1.0f + __expf(-v));
            const int row = rowBase + wave * 16 + quad * 4 + rr;
            C[(size_t)row * N + col] = (CT)v;
            pk[rr] = (bf16_t)v;
        }
        if (WT) {
            *(uint2*)(Ct + (size_t)col * M + rowBase + wave * 16 + quad * 4) = *(const uint2*)pk;
        }
    }
}

// ---------------------------------------------------------------- Z = noise*exp(logstd)+mean (fp32), hi/lo split:
// ZA row i = [hi(64) | hi | lo | lo];  ZB row j = [hi(64) | lo | hi | lo]  (ZB == B-transposed for gemm_bt)
__global__ __launch_bounds__(256) void z_split_kernel(
    const float* __restrict__ noise, const float* __restrict__ mean,
    const float* __restrict__ logstd,
    bf16_t* __restrict__ ZA, bf16_t* __restrict__ ZB)
{
    const int idx = blockIdx.x * 256 + threadIdx.x;  // < N*DH2
    const int i = idx >> 6, c = idx & 63;
    float z = noise[idx] * __expf(logstd[idx]) + mean[idx];
    bf16_t zhi = (bf16_t)z;
    bf16_t zlo = (bf16_t)(z - (float)zhi);
    const size_t rb = (size_t)i * 256;
    ZA[rb + c]       = zhi;
    ZA[rb + 64 + c]  = zhi;
    ZA[rb + 128 + c] = zlo;
    ZA[rb + 192 + c] = zlo;
    ZB[rb + c]       = zhi;
    ZB[rb + 64 + c]  = zlo;
    ZB[rb + 128 + c] = zhi;
    ZB[rb + 192 + c] = zlo;
}

// ================================================================ launch
extern "C" void kernel_launch(void* const* d_in, const int* in_sizes, int n_in,
                              void* d_out, int out_size, void* d_ws, size_t ws_size,
                              hipStream_t stream)
{
    const float* X     = (const float*)d_in[0];
    const int*   adj   = (const int*)  d_in[1];
    const float* noise = (const float*)d_in[2];
    const float* W0    = (const float*)d_in[3];
    const float* a0    = (const float*)d_in[4];
    const float* W1    = (const float*)d_in[5];
    const float* a1    = (const float*)d_in[6];
    const float* W2    = (const float*)d_in[7];
    const float* a2    = (const float*)d_in[8];
    float* out = (float*)d_out;

    char* ws = (char*)d_ws;
    size_t off = 0;
    auto alloc = [&](size_t bytes) { char* p = ws + off; off += (bytes + 255) & ~(size_t)255; return p; };

    unsigned long long* mask = (unsigned long long*)alloc((size_t)NWORDS * 8);    // 2 MB
    bf16_t* Xb    = (bf16_t*)alloc((size_t)N_NODES * DIM_IN * 2);                 // 4 MB
    bf16_t* W0T   = (bf16_t*)alloc((size_t)DH1 * DIM_IN * 2);                     // 0.25 MB
    bf16_t* W12T  = (bf16_t*)alloc((size_t)128 * DH1 * 2);                        // 64 KB
    bf16_t* h0b   = (bf16_t*)alloc((size_t)N_NODES * DH1 * 2);                    // 2 MB
    bf16_t* h0T   = (bf16_t*)alloc((size_t)DH1 * N_NODES * 2);                    // 2 MB
    float*  hid32 = (float*)alloc((size_t)N_NODES * DH1 * 4);                     // 4 MB
    bf16_t* hidb  = (bf16_t*)alloc((size_t)N_NODES * DH1 * 2);                    // 2 MB
    bf16_t* h12b  = (bf16_t*)alloc((size_t)N_NODES * 128 * 2);                    // 1 MB
    bf16_t* h12T  = (bf16_t*)alloc((size_t)128 * N_NODES * 2);                    // 1 MB
    float*  meanb   = (float*)alloc((size_t)N_NODES * DH2 * 4);                   // 1 MB
    float*  logstdb = (float*)alloc((size_t)N_NODES * DH2 * 4);                   // 1 MB
    bf16_t* ZA    = (bf16_t*)alloc((size_t)N_NODES * 256 * 2);                    // 2 MB
    bf16_t* ZB    = (bf16_t*)alloc((size_t)N_NODES * 256 * 2);                    // 2 MB
    float* f1   = (float*)alloc((size_t)N_NODES * 4);
    float* f2   = (float*)alloc((size_t)N_NODES * 4);
    float* mrow = (float*)alloc((size_t)N_NODES * 4);
    float* srow = (float*)alloc((size_t)N_NODES * 4);
    (void)ws_size; (void)in_sizes; (void)n_in; (void)out_size;

    dim3 blk(256);

    // zero accumulation buffers (harness poisons ws with 0xAA)
    hipMemsetAsync(hid32,   0, (size_t)N_NODES * DH1 * 4, stream);
    hipMemsetAsync(meanb,   0, (size_t)N_NODES * DH2 * 4, stream);
    hipMemsetAsync(logstdb, 0, (size_t)N_NODES * DH2 * 4, stream);

    // input conversions
    cvt_kernel<<<(N_NODES * DIM_IN / 4 + 255) / 256, blk, 0, stream>>>(X, Xb, N_NODES * DIM_IN / 4);
    cvtT_kernel<<<(DH1 * DIM_IN + 255) / 256, blk, 0, stream>>>(W0, W0T, DH1, DIM_IN);
    w12t_kernel<<<(128 * DH1 + 255) / 256, blk, 0, stream>>>(W1, W2, W12T);
    pack_mask_kernel<<<2048, blk, 0, stream>>>(adj, mask);

    // ---- layer 0
    gemm_bt_kernel<0, 1, bf16_t><<<dim3(DH1 / 64, N_NODES / 64), blk, 0, stream>>>(
        Xb, W0T, h0b, h0T, N_NODES, DH1, DIM_IN);
    f1f2_kernel<<<N_NODES / 4, blk, 0, stream>>>(h0b, a0, f1, f2, DH1, DH1);
    rowstats_kernel<<<N_NODES / 4, blk, 0, stream>>>(mask, f1, f2, mrow, srow);
    attn_fused_kernel<2048><<<dim3(DH1 / 64, N_NODES / 64, 2), blk, 0, stream>>>(
        mask, f1, f2, mrow, srow, h0T, hid32, DH1);
    cvt_kernel<<<(N_NODES * DH1 / 4 + 255) / 256, blk, 0, stream>>>(hid32, hidb, N_NODES * DH1 / 4);

    // ---- h1|h2 = hid @ [W1|W2]
    gemm_bt_kernel<0, 1, bf16_t><<<dim3(2, N_NODES / 64), blk, 0, stream>>>(
        hidb, W12T, h12b, h12T, N_NODES, 128, DH1);

    // ---- layer 1: mean
    f1f2_kernel<<<N_NODES / 4, blk, 0, stream>>>(h12b, a1, f1, f2, DH2, 128);
    rowstats_kernel<<<N_NODES / 4, blk, 0, stream>>>(mask, f1, f2, mrow, srow);
    attn_fused_kernel<1024><<<dim3(1, N_NODES / 64, 4), blk, 0, stream>>>(
        mask, f1, f2, mrow, srow, h12T, meanb, DH2);

    // ---- layer 2: logstd
    f1f2_kernel<<<N_NODES / 4, blk, 0, stream>>>(h12b + 64, a2, f1, f2, DH2, 128);
    rowstats_kernel<<<N_NODES / 4, blk, 0, stream>>>(mask, f1, f2, mrow, srow);
    attn_fused_kernel<1024><<<dim3(1, N_NODES / 64, 4), blk, 0, stream>>>(
        mask, f1, f2, mrow, srow, h12T + (size_t)64 * N_NODES, logstdb, DH2);

    // ---- Z (hi/lo split) and A_pred = sigmoid(Z @ Z^T), K=256 exact
    z_split_kernel<<<(N_NODES * DH2) / 256, blk, 0, stream>>>(noise, meanb, logstdb, ZA, ZB);
    gemm_bt_kernel<1, 0, float><<<dim3(N_NODES / 64, N_NODES / 64), blk, 0, stream>>>(
        ZA, ZB, out, nullptr, N_NODES, N_NODES, 256);
}

// Round 6
// 438.081 us; speedup vs baseline: 1.6357x; 1.2131x over previous
//
#include <hip/hip_runtime.h>
#include <hip/hip_bf16.h>
#include <math.h>

#define N_NODES 4096
#define DIM_IN  512
#define DH1     256
#define DH2     64
#define ALPHA   0.2f
#define ROW_WORDS (N_NODES / 64)
#define NWORDS  (N_NODES * ROW_WORDS)
#define L2E     1.4426950408889634f

typedef __bf16 bf16_t;
typedef bf16_t bf16x8 __attribute__((ext_vector_type(8)));
typedef float  f32x4  __attribute__((ext_vector_type(4)));

// ---------------------------------------------------------------- fp32 -> bf16 (straight)
__global__ __launch_bounds__(256) void cvt_kernel(
    const float* __restrict__ in, bf16_t* __restrict__ out, int n4)
{
    int i = blockIdx.x * 256 + threadIdx.x;
    if (i < n4) {
        float4 v = ((const float4*)in)[i];
        bf16_t o[4] = {(bf16_t)v.x, (bf16_t)v.y, (bf16_t)v.z, (bf16_t)v.w};
        *(uint2*)(out + (size_t)i * 4) = *(const uint2*)o;
    }
}

// ---------------------------------------------------------------- fp32 [K][N] -> bf16 [N][K]
__global__ __launch_bounds__(256) void cvtT_kernel(
    const float* __restrict__ in, bf16_t* __restrict__ out, int Nn, int Kk)
{
    int o = blockIdx.x * 256 + threadIdx.x;
    if (o < Nn * Kk) {
        int n = o / Kk, k = o - n * Kk;
        out[o] = (bf16_t)in[(size_t)k * Nn + n];
    }
}

// ---------------------------------------------------------------- W12T[128][256]
__global__ __launch_bounds__(256) void w12t_kernel(
    const float* __restrict__ W1, const float* __restrict__ W2, bf16_t* __restrict__ out)
{
    int o = blockIdx.x * 256 + threadIdx.x;
    int n = o >> 8, k = o & 255;
    const float* W = (n < 64) ? W1 : W2;
    out[o] = (bf16_t)W[(size_t)k * 64 + (n & 63)];
}

// ---------------------------------------------------------------- pack adj -> bitmask
__global__ __launch_bounds__(256) void pack_mask_kernel(
    const int* __restrict__ adj, unsigned long long* __restrict__ mask)
{
    const int lane = threadIdx.x & 63;
    int gw = (blockIdx.x * 256 + threadIdx.x) >> 6;
    const int nw = (gridDim.x * 256) >> 6;
    for (int w = gw; w < NWORDS; w += nw) {
        int v = adj[(size_t)w * 64 + lane];
        unsigned long long b = __ballot(v > 0);
        if (lane == 0) mask[w] = b;
    }
}

// ---------------------------------------------------------------- f1/f2
__global__ __launch_bounds__(256) void f1f2_kernel(
    const bf16_t* __restrict__ h, const float* __restrict__ a,
    float* __restrict__ f1, float* __restrict__ f2, int d, int ld)
{
    const int wave = threadIdx.x >> 6, lane = threadIdx.x & 63;
    const int row = blockIdx.x * 4 + wave;
    const bf16_t* hr = h + (size_t)row * ld;
    float s1 = 0.f, s2 = 0.f;
    for (int c = lane; c < d; c += 64) {
        float hv = (float)hr[c];
        s1 += hv * a[c];
        s2 += hv * a[d + c];
    }
    for (int off = 32; off; off >>= 1) {
        s1 += __shfl_down(s1, off);
        s2 += __shfl_down(s2, off);
    }
    if (lane == 0) { f1[row] = s1; f2[row] = s2; }
}

// ---------------------------------------------------------------- per-row softmax stats
__global__ __launch_bounds__(256) void rowstats_kernel(
    const unsigned long long* __restrict__ mask,
    const float* __restrict__ f1, const float* __restrict__ f2,
    float* __restrict__ mrow, float* __restrict__ srow)
{
    __shared__ float f2s[N_NODES];
    const int tid = threadIdx.x;
    for (int j = tid; j < N_NODES; j += 256) f2s[j] = f2[j];
    __syncthreads();
    const int wave = tid >> 6, lane = tid & 63;
    const int row = blockIdx.x * 4 + wave;
    const float fi = f1[row];
    const unsigned long long* mw = mask + (size_t)row * ROW_WORDS;

    float mx = -3.0e38f;
    for (int t = 0; t < ROW_WORDS; ++t) {
        unsigned long long w = mw[t];
        if ((w >> lane) & 1ull) {
            float e = fi + f2s[t * 64 + lane];
            e = e > 0.f ? e : ALPHA * e;
            mx = fmaxf(mx, e);
        }
    }
    for (int off = 32; off; off >>= 1) mx = fmaxf(mx, __shfl_xor(mx, off));

    float sum = 0.f;
    if (mx > -2.0e38f) {
        for (int t = 0; t < ROW_WORDS; ++t) {
            unsigned long long w = mw[t];
            if ((w >> lane) & 1ull) {
                float e = fi + f2s[t * 64 + lane];
                e = e > 0.f ? e : ALPHA * e;
                sum += __expf(e - mx);
            }
        }
    }
    for (int off = 32; off; off >>= 1) sum += __shfl_xor(sum, off);
    if (lane == 0) {
        if (mx > -2.0e38f) { mrow[row] = mx; srow[row] = sum; }
        else               { mrow[row] = 0.f; srow[row] = 0.f; }
    }
}

// ---------------------------------------------------------------- fused attention GEMM with K-split partials
// outP[split][row][col] = sum_{k in split} P(row,k) * BT[col][k]
// P generated in registers: mask words pre-hoisted (whole split, contiguous), f2 slice in LDS.
// Block: 64 rows x NT*16 cols. grid = (N/(NT*16), 64, 4096/KLEN).
template <int NT, int KLEN>
__global__ __launch_bounds__(256) void attn_fused_kernel(
    const unsigned long long* __restrict__ maskw,
    const float* __restrict__ f1, const float* __restrict__ f2,
    const float* __restrict__ mrow, const float* __restrict__ srow,
    const bf16_t* __restrict__ BT,   // [N][4096]
    float* __restrict__ outP, int N)
{
    __shared__ float f2s[KLEN];
    const int tid = threadIdx.x;
    const int wave = tid >> 6, lane = tid & 63, quad = lane >> 4, l16 = lane & 15;
    const int colBase = blockIdx.x * (NT * 16);
    const int rowBase = blockIdx.y * 64;
    const int kBeg = blockIdx.z * KLEN;
    const int r = rowBase + wave * 16 + l16;

    // stage f2 slice to LDS (float4)
    if (tid < KLEN / 4) ((float4*)f2s)[tid] = *(const float4*)(f2 + kBeg + tid * 4);

    // hoist this row's mask words for the whole split (contiguous)
    unsigned long long mwr[KLEN / 64];
    #pragma unroll
    for (int w = 0; w < KLEN / 64; ++w)
        mwr[w] = maskw[(size_t)r * ROW_WORDS + (kBeg >> 6) + w];

    // per-row softmax constants: p = exp2(e*L2E + Cr)  [masked], or 1/N uniform
    const float m = mrow[r], s = srow[r];
    const bool uni = (s <= 0.f);
    const float Cr = uni ? 0.f : (-m * L2E - __log2f(s));
    const float f1r = f1[r];
    const float puni = 1.0f / (float)N_NODES;

    __syncthreads();

    f32x4 acc[NT] = {};
    for (int k0 = 0; k0 < KLEN; k0 += 32) {
        const int kc = k0 + quad * 8;
        const unsigned bits = (unsigned)((mwr[kc >> 6] >> (kc & 63)) & 0xFFull);
        bf16x8 av;
        #pragma unroll
        for (int j = 0; j < 8; ++j) {
            float x = f1r + f2s[kc + j];
            float e = fmaxf(x, ALPHA * x);
            float p = ((bits >> j) & 1u) ? exp2f(__builtin_fmaf(e, L2E, Cr)) : 0.f;
            av[j] = (bf16_t)(uni ? puni : p);
        }
        #pragma unroll
        for (int t = 0; t < NT; ++t) {
            bf16x8 bv = *(const bf16x8*)(BT + (size_t)(colBase + t * 16 + l16) * N_NODES + kBeg + kc);
            acc[t] = __builtin_amdgcn_mfma_f32_16x16x32_bf16(av, bv, acc[t], 0, 0, 0);
        }
    }

    float* outBase = outP + (size_t)blockIdx.z * N_NODES * N;
    #pragma unroll
    for (int t = 0; t < NT; ++t) {
        const int col = colBase + t * 16 + l16;
        #pragma unroll
        for (int rr = 0; rr < 4; ++rr) {
            const int row = rowBase + wave * 16 + quad * 4 + rr;
            outBase[(size_t)row * N + col] = acc[t][rr];
        }
    }
}

// ---------------------------------------------------------------- reduce K-split partials
// OT = bf16 or float. n elements, S splits.
template <typename OT>
__global__ __launch_bounds__(256) void reduce_kernel(
    const float* __restrict__ p, OT* __restrict__ out, int n4, int S)
{
    int i = blockIdx.x * 256 + threadIdx.x;
    if (i >= n4) return;
    float4 a = ((const float4*)p)[i];
    for (int s = 1; s < S; ++s) {
        float4 b = ((const float4*)p)[(size_t)s * n4 + i];
        a.x += b.x; a.y += b.y; a.z += b.z; a.w += b.w;
    }
    if constexpr (sizeof(OT) == 2) {
        bf16_t o[4] = {(bf16_t)a.x, (bf16_t)a.y, (bf16_t)a.z, (bf16_t)a.w};
        *(uint2*)((bf16_t*)out + (size_t)i * 4) = *(const uint2*)o;
    } else {
        ((float4*)out)[i] = a;
    }
}

// ---------------------------------------------------------------- LDS-free GEMM: C = A @ BT^T
template <int EP, int WT, typename CT>
__global__ __launch_bounds__(256) void gemm_bt_kernel(
    const bf16_t* __restrict__ A, const bf16_t* __restrict__ BT,
    CT* __restrict__ C, bf16_t* __restrict__ Ct, int M, int N, int K)
{
    const int tid = threadIdx.x;
    const int wave = tid >> 6, lane = tid & 63, quad = lane >> 4, l16 = lane & 15;
    const int colBase = blockIdx.x * 64, rowBase = blockIdx.y * 64;
    const int mr = rowBase + wave * 16 + l16;
    const bf16_t* Ap = A + (size_t)mr * K + quad * 8;

    f32x4 acc[4] = {};
    for (int k0 = 0; k0 < K; k0 += 32) {
        bf16x8 av = *(const bf16x8*)(Ap + k0);
        #pragma unroll
        for (int t = 0; t < 4; ++t) {
            bf16x8 bv = *(const bf16x8*)(BT + (size_t)(colBase + t * 16 + l16) * K + k0 + quad * 8);
            acc[t] = __builtin_amdgcn_mfma_f32_16x16x32_bf16(av, bv, acc[t], 0, 0, 0);
        }
    }
    #pragma unroll
    for (int t = 0; t < 4; ++t) {
        const int col = colBase + t * 16 + l16;
        bf16_t pk[4];
        #pragma unroll
        for (int rr = 0; rr < 4; ++rr) {
            float v = acc[t][rr];
            if (EP == 1) v = 1.0f / (1.0f + __expf(-v));
            const int row = rowBase + wave * 16 + quad * 4 + rr;
            C[(size_t)row * N + col] = (CT)v;
            pk[rr] = (bf16_t)v;
        }
        if (WT) {
            *(uint2*)(Ct + (size_t)col * M + rowBase + wave * 16 + quad * 4) = *(const uint2*)pk;
        }
    }
}

// ---------------------------------------------------------------- Z hi/lo split
__global__ __launch_bounds__(256) void z_split_kernel(
    const float* __restrict__ noise, const float* __restrict__ mean,
    const float* __restrict__ logstd,
    bf16_t* __restrict__ ZA, bf16_t* __restrict__ ZB)
{
    const int idx = blockIdx.x * 256 + threadIdx.x;
    const int i = idx >> 6, c = idx & 63;
    float z = noise[idx] * __expf(logstd[idx]) + mean[idx];
    bf16_t zhi = (bf16_t)z;
    bf16_t zlo = (bf16_t)(z - (float)zhi);
    const size_t rb = (size_t)i * 256;
    ZA[rb + c]       = zhi;
    ZA[rb + 64 + c]  = zhi;
    ZA[rb + 128 + c] = zlo;
    ZA[rb + 192 + c] = zlo;
    ZB[rb + c]       = zhi;
    ZB[rb + 64 + c]  = zlo;
    ZB[rb + 128 + c] = zhi;
    ZB[rb + 192 + c] = zlo;
}

// ================================================================ launch
extern "C" void kernel_launch(void* const* d_in, const int* in_sizes, int n_in,
                              void* d_out, int out_size, void* d_ws, size_t ws_size,
                              hipStream_t stream)
{
    const float* X     = (const float*)d_in[0];
    const int*   adj   = (const int*)  d_in[1];
    const float* noise = (const float*)d_in[2];
    const float* W0    = (const float*)d_in[3];
    const float* a0    = (const float*)d_in[4];
    const float* W1    = (const float*)d_in[5];
    const float* a1    = (const float*)d_in[6];
    const float* W2    = (const float*)d_in[7];
    const float* a2    = (const float*)d_in[8];
    float* out = (float*)d_out;

    char* ws = (char*)d_ws;
    size_t off = 0;
    auto alloc = [&](size_t bytes) { char* p = ws + off; off += (bytes + 255) & ~(size_t)255; return p; };

    unsigned long long* mask = (unsigned long long*)alloc((size_t)NWORDS * 8);    // 2 MB
    float*  part  = (float*)alloc((size_t)8 * N_NODES * DH1 * 4);                 // 32 MB (k-split partials, reused)
    bf16_t* Xb    = (bf16_t*)alloc((size_t)N_NODES * DIM_IN * 2);                 // 4 MB
    bf16_t* W0T   = (bf16_t*)alloc((size_t)DH1 * DIM_IN * 2);
    bf16_t* W12T  = (bf16_t*)alloc((size_t)128 * DH1 * 2);
    bf16_t* h0b   = (bf16_t*)alloc((size_t)N_NODES * DH1 * 2);                    // 2 MB
    bf16_t* h0T   = (bf16_t*)alloc((size_t)DH1 * N_NODES * 2);                    // 2 MB
    bf16_t* hidb  = (bf16_t*)alloc((size_t)N_NODES * DH1 * 2);                    // 2 MB
    bf16_t* h12b  = (bf16_t*)alloc((size_t)N_NODES * 128 * 2);                    // 1 MB
    bf16_t* h12T  = (bf16_t*)alloc((size_t)128 * N_NODES * 2);                    // 1 MB
    float*  meanb   = (float*)alloc((size_t)N_NODES * DH2 * 4);                   // 1 MB
    float*  logstdb = (float*)alloc((size_t)N_NODES * DH2 * 4);                   // 1 MB
    bf16_t* ZA    = (bf16_t*)alloc((size_t)N_NODES * 256 * 2);                    // 2 MB
    bf16_t* ZB    = (bf16_t*)alloc((size_t)N_NODES * 256 * 2);                    // 2 MB
    float* f1   = (float*)alloc((size_t)N_NODES * 4);
    float* f2   = (float*)alloc((size_t)N_NODES * 4);
    float* mrow = (float*)alloc((size_t)N_NODES * 4);
    float* srow = (float*)alloc((size_t)N_NODES * 4);
    (void)ws_size; (void)in_sizes; (void)n_in; (void)out_size;

    dim3 blk(256);

    // input conversions
    cvt_kernel<<<(N_NODES * DIM_IN / 4 + 255) / 256, blk, 0, stream>>>(X, Xb, N_NODES * DIM_IN / 4);
    cvtT_kernel<<<(DH1 * DIM_IN + 255) / 256, blk, 0, stream>>>(W0, W0T, DH1, DIM_IN);
    w12t_kernel<<<(128 * DH1 + 255) / 256, blk, 0, stream>>>(W1, W2, W12T);
    pack_mask_kernel<<<2048, blk, 0, stream>>>(adj, mask);

    // ---- layer 0: hid = P0 @ (X@W0)
    gemm_bt_kernel<0, 1, bf16_t><<<dim3(DH1 / 64, N_NODES / 64), blk, 0, stream>>>(
        Xb, W0T, h0b, h0T, N_NODES, DH1, DIM_IN);
    f1f2_kernel<<<N_NODES / 4, blk, 0, stream>>>(h0b, a0, f1, f2, DH1, DH1);
    rowstats_kernel<<<N_NODES / 4, blk, 0, stream>>>(mask, f1, f2, mrow, srow);
    attn_fused_kernel<16, 512><<<dim3(1, N_NODES / 64, 8), blk, 0, stream>>>(
        mask, f1, f2, mrow, srow, h0T, part, DH1);
    reduce_kernel<bf16_t><<<(N_NODES * DH1 / 4 + 255) / 256, blk, 0, stream>>>(
        part, hidb, N_NODES * DH1 / 4, 8);

    // ---- h1|h2 = hid @ [W1|W2]
    gemm_bt_kernel<0, 1, bf16_t><<<dim3(2, N_NODES / 64), blk, 0, stream>>>(
        hidb, W12T, h12b, h12T, N_NODES, 128, DH1);

    // ---- layer 1: mean
    f1f2_kernel<<<N_NODES / 4, blk, 0, stream>>>(h12b, a1, f1, f2, DH2, 128);
    rowstats_kernel<<<N_NODES / 4, blk, 0, stream>>>(mask, f1, f2, mrow, srow);
    attn_fused_kernel<4, 512><<<dim3(1, N_NODES / 64, 8), blk, 0, stream>>>(
        mask, f1, f2, mrow, srow, h12T, part, DH2);
    reduce_kernel<float><<<(N_NODES * DH2 / 4 + 255) / 256, blk, 0, stream>>>(
        part, meanb, N_NODES * DH2 / 4, 8);

    // ---- layer 2: logstd
    f1f2_kernel<<<N_NODES / 4, blk, 0, stream>>>(h12b + 64, a2, f1, f2, DH2, 128);
    rowstats_kernel<<<N_NODES / 4, blk, 0, stream>>>(mask, f1, f2, mrow, srow);
    attn_fused_kernel<4, 512><<<dim3(1, N_NODES / 64, 8), blk, 0, stream>>>(
        mask, f1, f2, mrow, srow, h12T + (size_t)64 * N_NODES, part, DH2);
    reduce_kernel<float><<<(N_NODES * DH2 / 4 + 255) / 256, blk, 0, stream>>>(
        part, logstdb, N_NODES * DH2 / 4, 8);

    // ---- Z (hi/lo split) and A_pred = sigmoid(Z @ Z^T), K=256 exact
    z_split_kernel<<<(N_NODES * DH2) / 256, blk, 0, stream>>>(noise, meanb, logstdb, ZA, ZB);
    gemm_bt_kernel<1, 0, float><<<dim3(N_NODES / 64, N_NODES / 64), blk, 0, stream>>>(
        ZA, ZB, out, nullptr, N_NODES, N_NODES, 256);
}

// Round 7
// 419.998 us; speedup vs baseline: 1.7061x; 1.0431x over previous
//
#include <hip/hip_runtime.h>
#include <hip/hip_bf16.h>
#include <math.h>

#define N_NODES 4096
#define DIM_IN  512
#define DH1     256
#define DH2     64
#define ALPHA   0.2f
#define ROW_WORDS (N_NODES / 64)
#define NWORDS  (N_NODES * ROW_WORDS)
#define L2E     1.4426950408889634f

typedef __bf16 bf16_t;
typedef bf16_t bf16x8 __attribute__((ext_vector_type(8)));
typedef float  f32x4  __attribute__((ext_vector_type(4)));

// ---------------------------------------------------------------- fp32 -> bf16 (straight)
__global__ __launch_bounds__(256) void cvt_kernel(
    const float* __restrict__ in, bf16_t* __restrict__ out, int n4)
{
    int i = blockIdx.x * 256 + threadIdx.x;
    if (i < n4) {
        float4 v = ((const float4*)in)[i];
        bf16_t o[4] = {(bf16_t)v.x, (bf16_t)v.y, (bf16_t)v.z, (bf16_t)v.w};
        *(uint2*)(out + (size_t)i * 4) = *(const uint2*)o;
    }
}

// ---------------------------------------------------------------- fp32 [K][N] -> bf16 [N][K]
__global__ __launch_bounds__(256) void cvtT_kernel(
    const float* __restrict__ in, bf16_t* __restrict__ out, int Nn, int Kk)
{
    int o = blockIdx.x * 256 + threadIdx.x;
    if (o < Nn * Kk) {
        int n = o / Kk, k = o - n * Kk;
        out[o] = (bf16_t)in[(size_t)k * Nn + n];
    }
}

// ---------------------------------------------------------------- W12T[128][256]
__global__ __launch_bounds__(256) void w12t_kernel(
    const float* __restrict__ W1, const float* __restrict__ W2, bf16_t* __restrict__ out)
{
    int o = blockIdx.x * 256 + threadIdx.x;
    int n = o >> 8, k = o & 255;
    const float* W = (n < 64) ? W1 : W2;
    out[o] = (bf16_t)W[(size_t)k * 64 + (n & 63)];
}

// ---------------------------------------------------------------- pack adj -> bitmask
__global__ __launch_bounds__(256) void pack_mask_kernel(
    const int* __restrict__ adj, unsigned long long* __restrict__ mask)
{
    const int lane = threadIdx.x & 63;
    int gw = (blockIdx.x * 256 + threadIdx.x) >> 6;
    const int nw = (gridDim.x * 256) >> 6;
    for (int w = gw; w < NWORDS; w += nw) {
        int v = adj[(size_t)w * 64 + lane];
        unsigned long long b = __ballot(v > 0);
        if (lane == 0) mask[w] = b;
    }
}

// ---------------------------------------------------------------- f1/f2 (layer 0, d=256)
__global__ __launch_bounds__(256) void f1f2_kernel(
    const bf16_t* __restrict__ h, const float* __restrict__ a,
    float* __restrict__ f1, float* __restrict__ f2, int d, int ld)
{
    const int wave = threadIdx.x >> 6, lane = threadIdx.x & 63;
    const int row = blockIdx.x * 4 + wave;
    const bf16_t* hr = h + (size_t)row * ld;
    float s1 = 0.f, s2 = 0.f;
    for (int c = lane; c < d; c += 64) {
        float hv = (float)hr[c];
        s1 += hv * a[c];
        s2 += hv * a[d + c];
    }
    for (int off = 32; off; off >>= 1) {
        s1 += __shfl_down(s1, off);
        s2 += __shfl_down(s2, off);
    }
    if (lane == 0) { f1[row] = s1; f2[row] = s2; }
}

// ---------------------------------------------------------------- f1/f2 dual (layers 1&2, d=64, ld=128)
__global__ __launch_bounds__(256) void f1f2_dual_kernel(
    const bf16_t* __restrict__ h12, const float* __restrict__ a1, const float* __restrict__ a2,
    float* __restrict__ f1b, float* __restrict__ f2b)
{
    const int l = blockIdx.y;
    const int wave = threadIdx.x >> 6, lane = threadIdx.x & 63;
    const int row = blockIdx.x * 4 + wave;
    const float* a = l ? a2 : a1;
    const bf16_t* hr = h12 + (size_t)row * 128 + l * 64;
    float hv = (float)hr[lane];
    float s1 = hv * a[lane];
    float s2 = hv * a[64 + lane];
    for (int off = 32; off; off >>= 1) {
        s1 += __shfl_down(s1, off);
        s2 += __shfl_down(s2, off);
    }
    if (lane == 0) { f1b[l * N_NODES + row] = s1; f2b[l * N_NODES + row] = s2; }
}

// ---------------------------------------------------------------- per-row softmax stats (LAYERS: grid.y selects)
__global__ __launch_bounds__(256) void rowstats_kernel(
    const unsigned long long* __restrict__ mask,
    const float* __restrict__ f1b, const float* __restrict__ f2b,
    float* __restrict__ mrowb, float* __restrict__ srowb)
{
    __shared__ float f2s[N_NODES];
    const int l = blockIdx.y;
    const float* f1 = f1b + (size_t)l * N_NODES;
    const float* f2 = f2b + (size_t)l * N_NODES;
    const int tid = threadIdx.x;
    for (int j = tid; j < N_NODES; j += 256) f2s[j] = f2[j];
    __syncthreads();
    const int wave = tid >> 6, lane = tid & 63;
    const int row = blockIdx.x * 4 + wave;
    const float fi = f1[row];
    const unsigned long long* mw = mask + (size_t)row * ROW_WORDS;

    float mx = -3.0e38f;
    for (int t = 0; t < ROW_WORDS; ++t) {
        unsigned long long w = mw[t];
        if ((w >> lane) & 1ull) {
            float e = fi + f2s[t * 64 + lane];
            e = e > 0.f ? e : ALPHA * e;
            mx = fmaxf(mx, e);
        }
    }
    for (int off = 32; off; off >>= 1) mx = fmaxf(mx, __shfl_xor(mx, off));

    float sum = 0.f;
    if (mx > -2.0e38f) {
        for (int t = 0; t < ROW_WORDS; ++t) {
            unsigned long long w = mw[t];
            if ((w >> lane) & 1ull) {
                float e = fi + f2s[t * 64 + lane];
                e = e > 0.f ? e : ALPHA * e;
                sum += __expf(e - mx);
            }
        }
    }
    for (int off = 32; off; off >>= 1) sum += __shfl_xor(sum, off);
    if (lane == 0) {
        if (mx > -2.0e38f) { mrowb[l * N_NODES + row] = mx; srowb[l * N_NODES + row] = sum; }
        else               { mrowb[l * N_NODES + row] = 0.f; srowb[l * N_NODES + row] = 0.f; }
    }
}

// ---------------------------------------------------------------- fused attention GEMM, layer 0
// outP[split][row][col], P generated in registers.
template <int NT, int KLEN>
__global__ __launch_bounds__(256) void attn_fused_kernel(
    const unsigned long long* __restrict__ maskw,
    const float* __restrict__ f1, const float* __restrict__ f2,
    const float* __restrict__ mrow, const float* __restrict__ srow,
    const bf16_t* __restrict__ BT, float* __restrict__ outP, int N)
{
    __shared__ float f2s[KLEN];
    const int tid = threadIdx.x;
    const int wave = tid >> 6, lane = tid & 63, quad = lane >> 4, l16 = lane & 15;
    const int colBase = blockIdx.x * (NT * 16);
    const int rowBase = blockIdx.y * 64;
    const int kBeg = blockIdx.z * KLEN;
    const int r = rowBase + wave * 16 + l16;

    if (tid < KLEN / 4) ((float4*)f2s)[tid] = *(const float4*)(f2 + kBeg + tid * 4);

    unsigned long long mwr[KLEN / 64];
    #pragma unroll
    for (int w = 0; w < KLEN / 64; ++w)
        mwr[w] = maskw[(size_t)r * ROW_WORDS + (kBeg >> 6) + w];

    const float m = mrow[r], s = srow[r];
    const bool uni = (s <= 0.f);
    const float Cr = uni ? 0.f : (-m * L2E - __log2f(s));
    const float f1r = f1[r];
    const float puni = 1.0f / (float)N_NODES;

    __syncthreads();

    f32x4 acc[NT] = {};
    for (int k0 = 0; k0 < KLEN; k0 += 32) {
        const int kc = k0 + quad * 8;
        const unsigned bits = (unsigned)((mwr[kc >> 6] >> (kc & 63)) & 0xFFull);
        bf16x8 av;
        #pragma unroll
        for (int j = 0; j < 8; ++j) {
            float x = f1r + f2s[kc + j];
            float e = fmaxf(x, ALPHA * x);
            float p = ((bits >> j) & 1u) ? exp2f(__builtin_fmaf(e, L2E, Cr)) : 0.f;
            av[j] = (bf16_t)(uni ? puni : p);
        }
        #pragma unroll
        for (int t = 0; t < NT; ++t) {
            bf16x8 bv = *(const bf16x8*)(BT + (size_t)(colBase + t * 16 + l16) * N_NODES + kBeg + kc);
            acc[t] = __builtin_amdgcn_mfma_f32_16x16x32_bf16(av, bv, acc[t], 0, 0, 0);
        }
    }

    float* outBase = outP + (size_t)blockIdx.z * N_NODES * N;
    #pragma unroll
    for (int t = 0; t < NT; ++t) {
        const int col = colBase + t * 16 + l16;
        #pragma unroll
        for (int rr = 0; rr < 4; ++rr) {
            const int row = rowBase + wave * 16 + quad * 4 + rr;
            outBase[(size_t)row * N + col] = acc[t][rr];
        }
    }
}

// ---------------------------------------------------------------- fused attention, layers 1&2 in one launch
// grid (2, 64, 8): x = layer. outP layout [split][layer][4096][64].
template <int KLEN>
__global__ __launch_bounds__(256) void attn12_kernel(
    const unsigned long long* __restrict__ maskw,
    const float* __restrict__ f1b, const float* __restrict__ f2b,
    const float* __restrict__ mrowb, const float* __restrict__ srowb,
    const bf16_t* __restrict__ h12T, float* __restrict__ outP)
{
    __shared__ float f2s[KLEN];
    const int l = blockIdx.x;
    const float* f1 = f1b + (size_t)l * N_NODES;
    const float* f2 = f2b + (size_t)l * N_NODES;
    const bf16_t* BT = h12T + (size_t)l * 64 * N_NODES;

    const int tid = threadIdx.x;
    const int wave = tid >> 6, lane = tid & 63, quad = lane >> 4, l16 = lane & 15;
    const int rowBase = blockIdx.y * 64;
    const int kBeg = blockIdx.z * KLEN;
    const int r = rowBase + wave * 16 + l16;

    if (tid < KLEN / 4) ((float4*)f2s)[tid] = *(const float4*)(f2 + kBeg + tid * 4);

    unsigned long long mwr[KLEN / 64];
    #pragma unroll
    for (int w = 0; w < KLEN / 64; ++w)
        mwr[w] = maskw[(size_t)r * ROW_WORDS + (kBeg >> 6) + w];

    const float m = mrowb[l * N_NODES + r], s = srowb[l * N_NODES + r];
    const bool uni = (s <= 0.f);
    const float Cr = uni ? 0.f : (-m * L2E - __log2f(s));
    const float f1r = f1[r];
    const float puni = 1.0f / (float)N_NODES;

    __syncthreads();

    f32x4 acc[4] = {};
    for (int k0 = 0; k0 < KLEN; k0 += 32) {
        const int kc = k0 + quad * 8;
        const unsigned bits = (unsigned)((mwr[kc >> 6] >> (kc & 63)) & 0xFFull);
        bf16x8 av;
        #pragma unroll
        for (int j = 0; j < 8; ++j) {
            float x = f1r + f2s[kc + j];
            float e = fmaxf(x, ALPHA * x);
            float p = ((bits >> j) & 1u) ? exp2f(__builtin_fmaf(e, L2E, Cr)) : 0.f;
            av[j] = (bf16_t)(uni ? puni : p);
        }
        #pragma unroll
        for (int t = 0; t < 4; ++t) {
            bf16x8 bv = *(const bf16x8*)(BT + (size_t)(t * 16 + l16) * N_NODES + kBeg + kc);
            acc[t] = __builtin_amdgcn_mfma_f32_16x16x32_bf16(av, bv, acc[t], 0, 0, 0);
        }
    }

    float* outBase = outP + ((size_t)blockIdx.z * 2 + l) * (N_NODES * DH2);
    #pragma unroll
    for (int t = 0; t < 4; ++t) {
        const int col = t * 16 + l16;
        #pragma unroll
        for (int rr = 0; rr < 4; ++rr) {
            const int row = rowBase + wave * 16 + quad * 4 + rr;
            outBase[(size_t)row * DH2 + col] = acc[t][rr];
        }
    }
}

// ---------------------------------------------------------------- reduce K-split partials -> bf16 (layer 0)
__global__ __launch_bounds__(256) void reduce_kernel(
    const float* __restrict__ p, bf16_t* __restrict__ out, int n4, int S)
{
    int i = blockIdx.x * 256 + threadIdx.x;
    if (i >= n4) return;
    float4 a = ((const float4*)p)[i];
    for (int s = 1; s < S; ++s) {
        float4 b = ((const float4*)p)[(size_t)s * n4 + i];
        a.x += b.x; a.y += b.y; a.z += b.z; a.w += b.w;
    }
    bf16_t o[4] = {(bf16_t)a.x, (bf16_t)a.y, (bf16_t)a.z, (bf16_t)a.w};
    *(uint2*)(out + (size_t)i * 4) = *(const uint2*)o;
}

// ---------------------------------------------------------------- reduce L1/L2 partials + Z + hi/lo split
// part layout [s][l][4096][64]; mean = l0, logstd = l1. Writes ZA/ZB directly.
__global__ __launch_bounds__(256) void reduce_z_kernel(
    const float* __restrict__ part, const float* __restrict__ noise,
    bf16_t* __restrict__ ZA, bf16_t* __restrict__ ZB)
{
    const int idx = blockIdx.x * 256 + threadIdx.x;   // < 4096*64
    const int stride = 2 * N_NODES * DH2;
    float mean = 0.f, ls = 0.f;
    #pragma unroll
    for (int s = 0; s < 8; ++s) {
        mean += part[(size_t)s * stride + idx];
        ls   += part[(size_t)s * stride + N_NODES * DH2 + idx];
    }
    float z = noise[idx] * __expf(ls) + mean;
    bf16_t zhi = (bf16_t)z;
    bf16_t zlo = (bf16_t)(z - (float)zhi);
    const int i = idx >> 6, c = idx & 63;
    const size_t rb = (size_t)i * 256;
    ZA[rb + c]       = zhi;
    ZA[rb + 64 + c]  = zhi;
    ZA[rb + 128 + c] = zlo;
    ZA[rb + 192 + c] = zlo;
    ZB[rb + c]       = zhi;
    ZB[rb + 64 + c]  = zlo;
    ZB[rb + 128 + c] = zhi;
    ZB[rb + 192 + c] = zlo;
}

// ---------------------------------------------------------------- LDS-free GEMM (dense layers): C = A @ BT^T
template <int WT>
__global__ __launch_bounds__(256) void gemm_bt_kernel(
    const bf16_t* __restrict__ A, const bf16_t* __restrict__ BT,
    bf16_t* __restrict__ C, bf16_t* __restrict__ Ct, int M, int N, int K)
{
    const int tid = threadIdx.x;
    const int wave = tid >> 6, lane = tid & 63, quad = lane >> 4, l16 = lane & 15;
    const int colBase = blockIdx.x * 64, rowBase = blockIdx.y * 64;
    const int mr = rowBase + wave * 16 + l16;
    const bf16_t* Ap = A + (size_t)mr * K + quad * 8;

    f32x4 acc[4] = {};
    for (int k0 = 0; k0 < K; k0 += 32) {
        bf16x8 av = *(const bf16x8*)(Ap + k0);
        #pragma unroll
        for (int t = 0; t < 4; ++t) {
            bf16x8 bv = *(const bf16x8*)(BT + (size_t)(colBase + t * 16 + l16) * K + k0 + quad * 8);
            acc[t] = __builtin_amdgcn_mfma_f32_16x16x32_bf16(av, bv, acc[t], 0, 0, 0);
        }
    }
    #pragma unroll
    for (int t = 0; t < 4; ++t) {
        const int col = colBase + t * 16 + l16;
        bf16_t pk[4];
        #pragma unroll
        for (int rr = 0; rr < 4; ++rr) {
            float v = acc[t][rr];
            const int row = rowBase + wave * 16 + quad * 4 + rr;
            C[(size_t)row * N + col] = (bf16_t)v;
            pk[rr] = (bf16_t)v;
        }
        if (WT) {
            *(uint2*)(Ct + (size_t)col * M + rowBase + wave * 16 + quad * 4) = *(const uint2*)pk;
        }
    }
}

// ---------------------------------------------------------------- final: sigmoid(ZA @ ZB^T), 64x256 tile
template <int NT>
__global__ __launch_bounds__(256) void zzt_sigmoid_kernel(
    const bf16_t* __restrict__ ZA, const bf16_t* __restrict__ ZB, float* __restrict__ C)
{
    const int tid = threadIdx.x;
    const int wave = tid >> 6, lane = tid & 63, quad = lane >> 4, l16 = lane & 15;
    const int colBase = blockIdx.x * (NT * 16), rowBase = blockIdx.y * 64;
    const int mr = rowBase + wave * 16 + l16;
    const bf16_t* Ap = ZA + (size_t)mr * 256 + quad * 8;

    f32x4 acc[NT] = {};
    for (int k0 = 0; k0 < 256; k0 += 32) {
        bf16x8 av = *(const bf16x8*)(Ap + k0);
        #pragma unroll
        for (int t = 0; t < NT; ++t) {
            bf16x8 bv = *(const bf16x8*)(ZB + (size_t)(colBase + t * 16 + l16) * 256 + k0 + quad * 8);
            acc[t] = __builtin_amdgcn_mfma_f32_16x16x32_bf16(av, bv, acc[t], 0, 0, 0);
        }
    }
    #pragma unroll
    for (int t = 0; t < NT; ++t) {
        const int col = colBase + t * 16 + l16;
        #pragma unroll
        for (int rr = 0; rr < 4; ++rr) {
            const int row = rowBase + wave * 16 + quad * 4 + rr;
            float x = acc[t][rr];
            float v = __builtin_amdgcn_rcpf(1.0f + exp2f(-x * L2E));
            C[(size_t)row * N_NODES + col] = v;
        }
    }
}

// ================================================================ launch
extern "C" void kernel_launch(void* const* d_in, const int* in_sizes, int n_in,
                              void* d_out, int out_size, void* d_ws, size_t ws_size,
                              hipStream_t stream)
{
    const float* X     = (const float*)d_in[0];
    const int*   adj   = (const int*)  d_in[1];
    const float* noise = (const float*)d_in[2];
    const float* W0    = (const float*)d_in[3];
    const float* a0    = (const float*)d_in[4];
    const float* W1    = (const float*)d_in[5];
    const float* a1    = (const float*)d_in[6];
    const float* W2    = (const float*)d_in[7];
    const float* a2    = (const float*)d_in[8];
    float* out = (float*)d_out;

    char* ws = (char*)d_ws;
    size_t off = 0;
    auto alloc = [&](size_t bytes) { char* p = ws + off; off += (bytes + 255) & ~(size_t)255; return p; };

    unsigned long long* mask = (unsigned long long*)alloc((size_t)NWORDS * 8);    // 2 MB
    float*  part  = (float*)alloc((size_t)8 * N_NODES * DH1 * 4);                 // 32 MB
    bf16_t* Xb    = (bf16_t*)alloc((size_t)N_NODES * DIM_IN * 2);                 // 4 MB
    bf16_t* W0T   = (bf16_t*)alloc((size_t)DH1 * DIM_IN * 2);
    bf16_t* W12T  = (bf16_t*)alloc((size_t)128 * DH1 * 2);
    bf16_t* h0b   = (bf16_t*)alloc((size_t)N_NODES * DH1 * 2);                    // 2 MB
    bf16_t* h0T   = (bf16_t*)alloc((size_t)DH1 * N_NODES * 2);                    // 2 MB
    bf16_t* hidb  = (bf16_t*)alloc((size_t)N_NODES * DH1 * 2);                    // 2 MB
    bf16_t* h12b  = (bf16_t*)alloc((size_t)N_NODES * 128 * 2);                    // 1 MB
    bf16_t* h12T  = (bf16_t*)alloc((size_t)128 * N_NODES * 2);                    // 1 MB
    bf16_t* ZA    = (bf16_t*)alloc((size_t)N_NODES * 256 * 2);                    // 2 MB
    bf16_t* ZB    = (bf16_t*)alloc((size_t)N_NODES * 256 * 2);                    // 2 MB
    float* f1b  = (float*)alloc((size_t)2 * N_NODES * 4);
    float* f2b  = (float*)alloc((size_t)2 * N_NODES * 4);
    float* mrowb = (float*)alloc((size_t)2 * N_NODES * 4);
    float* srowb = (float*)alloc((size_t)2 * N_NODES * 4);
    (void)ws_size; (void)in_sizes; (void)n_in; (void)out_size;

    dim3 blk(256);

    // input conversions + mask pack
    cvt_kernel<<<(N_NODES * DIM_IN / 4 + 255) / 256, blk, 0, stream>>>(X, Xb, N_NODES * DIM_IN / 4);
    cvtT_kernel<<<(DH1 * DIM_IN + 255) / 256, blk, 0, stream>>>(W0, W0T, DH1, DIM_IN);
    w12t_kernel<<<(128 * DH1 + 255) / 256, blk, 0, stream>>>(W1, W2, W12T);
    pack_mask_kernel<<<2048, blk, 0, stream>>>(adj, mask);

    // ---- layer 0: hid = P0 @ (X@W0)
    gemm_bt_kernel<1><<<dim3(DH1 / 64, N_NODES / 64), blk, 0, stream>>>(
        Xb, W0T, h0b, h0T, N_NODES, DH1, DIM_IN);
    f1f2_kernel<<<N_NODES / 4, blk, 0, stream>>>(h0b, a0, f1b, f2b, DH1, DH1);
    rowstats_kernel<<<dim3(N_NODES / 4, 1), blk, 0, stream>>>(mask, f1b, f2b, mrowb, srowb);
    attn_fused_kernel<16, 512><<<dim3(1, N_NODES / 64, 8), blk, 0, stream>>>(
        mask, f1b, f2b, mrowb, srowb, h0T, part, DH1);
    reduce_kernel<<<(N_NODES * DH1 / 4 + 255) / 256, blk, 0, stream>>>(
        part, hidb, N_NODES * DH1 / 4, 8);

    // ---- h1|h2 = hid @ [W1|W2]
    gemm_bt_kernel<1><<<dim3(2, N_NODES / 64), blk, 0, stream>>>(
        hidb, W12T, h12b, h12T, N_NODES, 128, DH1);

    // ---- layers 1&2 merged: mean / logstd
    f1f2_dual_kernel<<<dim3(N_NODES / 4, 2), blk, 0, stream>>>(h12b, a1, a2, f1b, f2b);
    rowstats_kernel<<<dim3(N_NODES / 4, 2), blk, 0, stream>>>(mask, f1b, f2b, mrowb, srowb);
    attn12_kernel<512><<<dim3(2, N_NODES / 64, 8), blk, 0, stream>>>(
        mask, f1b, f2b, mrowb, srowb, h12T, part);
    reduce_z_kernel<<<(N_NODES * DH2) / 256, blk, 0, stream>>>(part, noise, ZA, ZB);

    // ---- A_pred = sigmoid(Z @ Z^T), K=256 exact hi/lo
    zzt_sigmoid_kernel<16><<<dim3(N_NODES / 256, N_NODES / 64), blk, 0, stream>>>(ZA, ZB, out);
}

// Round 8
// 399.716 us; speedup vs baseline: 1.7927x; 1.0507x over previous
//
#include <hip/hip_runtime.h>
#include <hip/hip_bf16.h>
#include <math.h>

#define N_NODES 4096
#define DIM_IN  512
#define DH1     256
#define DH2     64
#define ALPHA   0.2f
#define ROW_WORDS (N_NODES / 64)
#define NWORDS  (N_NODES * ROW_WORDS)
#define L2E     1.4426950408889634f

typedef __bf16 bf16_t;
typedef bf16_t bf16x8 __attribute__((ext_vector_type(8)));
typedef float  f32x4  __attribute__((ext_vector_type(4)));

// ---------------------------------------------------------------- fp32 -> bf16 (straight)
__global__ __launch_bounds__(256) void cvt_kernel(
    const float* __restrict__ in, bf16_t* __restrict__ out, int n4)
{
    int i = blockIdx.x * 256 + threadIdx.x;
    if (i < n4) {
        float4 v = ((const float4*)in)[i];
        bf16_t o[4] = {(bf16_t)v.x, (bf16_t)v.y, (bf16_t)v.z, (bf16_t)v.w};
        *(uint2*)(out + (size_t)i * 4) = *(const uint2*)o;
    }
}

// ---------------------------------------------------------------- fp32 [K][N] -> bf16 [N][K]
__global__ __launch_bounds__(256) void cvtT_kernel(
    const float* __restrict__ in, bf16_t* __restrict__ out, int Nn, int Kk)
{
    int o = blockIdx.x * 256 + threadIdx.x;
    if (o < Nn * Kk) {
        int n = o / Kk, k = o - n * Kk;
        out[o] = (bf16_t)in[(size_t)k * Nn + n];
    }
}

// ---------------------------------------------------------------- W12T[128][256]
__global__ __launch_bounds__(256) void w12t_kernel(
    const float* __restrict__ W1, const float* __restrict__ W2, bf16_t* __restrict__ out)
{
    int o = blockIdx.x * 256 + threadIdx.x;
    int n = o >> 8, k = o & 255;
    const float* W = (n < 64) ? W1 : W2;
    out[o] = (bf16_t)W[(size_t)k * 64 + (n & 63)];
}

// ---------------------------------------------------------------- pack adj -> bitmask
__global__ __launch_bounds__(256) void pack_mask_kernel(
    const int* __restrict__ adj, unsigned long long* __restrict__ mask)
{
    const int lane = threadIdx.x & 63;
    int gw = (blockIdx.x * 256 + threadIdx.x) >> 6;
    const int nw = (gridDim.x * 256) >> 6;
    for (int w = gw; w < NWORDS; w += nw) {
        int v = adj[(size_t)w * 64 + lane];
        unsigned long long b = __ballot(v > 0);
        if (lane == 0) mask[w] = b;
    }
}

// ---------------------------------------------------------------- f1/f2 (layer 0, d=256)
__global__ __launch_bounds__(256) void f1f2_kernel(
    const bf16_t* __restrict__ h, const float* __restrict__ a,
    float* __restrict__ f1, float* __restrict__ f2, int d, int ld)
{
    const int wave = threadIdx.x >> 6, lane = threadIdx.x & 63;
    const int row = blockIdx.x * 4 + wave;
    const bf16_t* hr = h + (size_t)row * ld;
    float s1 = 0.f, s2 = 0.f;
    for (int c = lane; c < d; c += 64) {
        float hv = (float)hr[c];
        s1 += hv * a[c];
        s2 += hv * a[d + c];
    }
    for (int off = 32; off; off >>= 1) {
        s1 += __shfl_down(s1, off);
        s2 += __shfl_down(s2, off);
    }
    if (lane == 0) { f1[row] = s1; f2[row] = s2; }
}

// ---------------------------------------------------------------- f1/f2 dual (layers 1&2)
__global__ __launch_bounds__(256) void f1f2_dual_kernel(
    const bf16_t* __restrict__ h12, const float* __restrict__ a1, const float* __restrict__ a2,
    float* __restrict__ f1b, float* __restrict__ f2b)
{
    const int l = blockIdx.y;
    const int wave = threadIdx.x >> 6, lane = threadIdx.x & 63;
    const int row = blockIdx.x * 4 + wave;
    const float* a = l ? a2 : a1;
    const bf16_t* hr = h12 + (size_t)row * 128 + l * 64;
    float hv = (float)hr[lane];
    float s1 = hv * a[lane];
    float s2 = hv * a[64 + lane];
    for (int off = 32; off; off >>= 1) {
        s1 += __shfl_down(s1, off);
        s2 += __shfl_down(s2, off);
    }
    if (lane == 0) { f1b[l * N_NODES + row] = s1; f2b[l * N_NODES + row] = s2; }
}

// ---------------------------------------------------------------- per-row softmax stats
__global__ __launch_bounds__(256) void rowstats_kernel(
    const unsigned long long* __restrict__ mask,
    const float* __restrict__ f1b, const float* __restrict__ f2b,
    float* __restrict__ mrowb, float* __restrict__ srowb)
{
    __shared__ float f2s[N_NODES];
    const int l = blockIdx.y;
    const float* f1 = f1b + (size_t)l * N_NODES;
    const float* f2 = f2b + (size_t)l * N_NODES;
    const int tid = threadIdx.x;
    for (int j = tid; j < N_NODES; j += 256) f2s[j] = f2[j];
    __syncthreads();
    const int wave = tid >> 6, lane = tid & 63;
    const int row = blockIdx.x * 4 + wave;
    const float fi = f1[row];
    const unsigned long long* mw = mask + (size_t)row * ROW_WORDS;

    float mx = -3.0e38f;
    for (int t = 0; t < ROW_WORDS; ++t) {
        unsigned long long w = mw[t];
        if ((w >> lane) & 1ull) {
            float e = fi + f2s[t * 64 + lane];
            e = e > 0.f ? e : ALPHA * e;
            mx = fmaxf(mx, e);
        }
    }
    for (int off = 32; off; off >>= 1) mx = fmaxf(mx, __shfl_xor(mx, off));

    float sum = 0.f;
    if (mx > -2.0e38f) {
        for (int t = 0; t < ROW_WORDS; ++t) {
            unsigned long long w = mw[t];
            if ((w >> lane) & 1ull) {
                float e = fi + f2s[t * 64 + lane];
                e = e > 0.f ? e : ALPHA * e;
                sum += __expf(e - mx);
            }
        }
    }
    for (int off = 32; off; off >>= 1) sum += __shfl_xor(sum, off);
    if (lane == 0) {
        if (mx > -2.0e38f) { mrowb[l * N_NODES + row] = mx; srowb[l * N_NODES + row] = sum; }
        else               { mrowb[l * N_NODES + row] = 0.f; srowb[l * N_NODES + row] = 0.f; }
    }
}

// ---------------------------------------------------------------- fused attention GEMM, layer 0
// Batched B-loads: all NT fragments requested before use -> NT loads in flight.
template <int NT, int KLEN>
__global__ __launch_bounds__(256) void attn_fused_kernel(
    const unsigned long long* __restrict__ maskw,
    const float* __restrict__ f1, const float* __restrict__ f2,
    const float* __restrict__ mrow, const float* __restrict__ srow,
    const bf16_t* __restrict__ BT, float* __restrict__ outP, int N)
{
    __shared__ float f2s[KLEN];
    const int tid = threadIdx.x;
    const int wave = tid >> 6, lane = tid & 63, quad = lane >> 4, l16 = lane & 15;
    const int colBase = blockIdx.x * (NT * 16);
    const int rowBase = blockIdx.y * 64;
    const int kBeg = blockIdx.z * KLEN;
    const int r = rowBase + wave * 16 + l16;

    if (tid < KLEN / 4) ((float4*)f2s)[tid] = *(const float4*)(f2 + kBeg + tid * 4);

    unsigned long long mwr[KLEN / 64];
    #pragma unroll
    for (int w = 0; w < KLEN / 64; ++w)
        mwr[w] = maskw[(size_t)r * ROW_WORDS + (kBeg >> 6) + w];

    const float m = mrow[r], s = srow[r];
    const bool uni = (s <= 0.f);
    const float Cr = uni ? 0.f : (-m * L2E - __log2f(s));
    const float f1r = f1[r];
    const float puni = 1.0f / (float)N_NODES;

    __syncthreads();

    const bf16_t* Bp = BT + (size_t)(colBase + l16) * N_NODES + kBeg + quad * 8;

    f32x4 acc[NT] = {};
    for (int k0 = 0; k0 < KLEN; k0 += 32) {
        const int kc = k0 + quad * 8;
        bf16x8 bv[NT];
        #pragma unroll
        for (int t = 0; t < NT; ++t)
            bv[t] = *(const bf16x8*)(Bp + (size_t)t * 16 * N_NODES + k0);
        const unsigned bits = (unsigned)((mwr[kc >> 6] >> (kc & 63)) & 0xFFull);
        bf16x8 av;
        #pragma unroll
        for (int j = 0; j < 8; ++j) {
            float x = f1r + f2s[kc + j];
            float e = fmaxf(x, ALPHA * x);
            float p = ((bits >> j) & 1u) ? exp2f(__builtin_fmaf(e, L2E, Cr)) : 0.f;
            av[j] = (bf16_t)(uni ? puni : p);
        }
        #pragma unroll
        for (int t = 0; t < NT; ++t)
            acc[t] = __builtin_amdgcn_mfma_f32_16x16x32_bf16(av, bv[t], acc[t], 0, 0, 0);
    }

    float* outBase = outP + (size_t)blockIdx.z * N_NODES * N;
    #pragma unroll
    for (int t = 0; t < NT; ++t) {
        const int col = colBase + t * 16 + l16;
        #pragma unroll
        for (int rr = 0; rr < 4; ++rr) {
            const int row = rowBase + wave * 16 + quad * 4 + rr;
            outBase[(size_t)row * N + col] = acc[t][rr];
        }
    }
}

// ---------------------------------------------------------------- fused attention, layers 1&2; k-unroll x2 (8 loads in flight)
template <int KLEN>
__global__ __launch_bounds__(256) void attn12_kernel(
    const unsigned long long* __restrict__ maskw,
    const float* __restrict__ f1b, const float* __restrict__ f2b,
    const float* __restrict__ mrowb, const float* __restrict__ srowb,
    const bf16_t* __restrict__ h12T, float* __restrict__ outP)
{
    __shared__ float f2s[KLEN];
    const int l = blockIdx.x;
    const float* f1 = f1b + (size_t)l * N_NODES;
    const float* f2 = f2b + (size_t)l * N_NODES;
    const bf16_t* BT = h12T + (size_t)l * 64 * N_NODES;

    const int tid = threadIdx.x;
    const int wave = tid >> 6, lane = tid & 63, quad = lane >> 4, l16 = lane & 15;
    const int rowBase = blockIdx.y * 64;
    const int kBeg = blockIdx.z * KLEN;
    const int r = rowBase + wave * 16 + l16;

    if (tid < KLEN / 4) ((float4*)f2s)[tid] = *(const float4*)(f2 + kBeg + tid * 4);

    unsigned long long mwr[KLEN / 64];
    #pragma unroll
    for (int w = 0; w < KLEN / 64; ++w)
        mwr[w] = maskw[(size_t)r * ROW_WORDS + (kBeg >> 6) + w];

    const float m = mrowb[l * N_NODES + r], s = srowb[l * N_NODES + r];
    const bool uni = (s <= 0.f);
    const float Cr = uni ? 0.f : (-m * L2E - __log2f(s));
    const float f1r = f1[r];
    const float puni = 1.0f / (float)N_NODES;

    __syncthreads();

    const bf16_t* Bp = BT + (size_t)l16 * N_NODES + kBeg + quad * 8;

    f32x4 acc[4] = {};
    for (int k0 = 0; k0 < KLEN; k0 += 64) {
        const int kc0 = k0 + quad * 8, kc1 = k0 + 32 + quad * 8;
        bf16x8 bv[8];
        #pragma unroll
        for (int t = 0; t < 4; ++t) {
            bv[t]     = *(const bf16x8*)(Bp + (size_t)t * 16 * N_NODES + k0);
            bv[4 + t] = *(const bf16x8*)(Bp + (size_t)t * 16 * N_NODES + k0 + 32);
        }
        const unsigned bits0 = (unsigned)((mwr[kc0 >> 6] >> (kc0 & 63)) & 0xFFull);
        const unsigned bits1 = (unsigned)((mwr[kc1 >> 6] >> (kc1 & 63)) & 0xFFull);
        bf16x8 av0, av1;
        #pragma unroll
        for (int j = 0; j < 8; ++j) {
            float x0 = f1r + f2s[kc0 + j];
            float e0 = fmaxf(x0, ALPHA * x0);
            float p0 = ((bits0 >> j) & 1u) ? exp2f(__builtin_fmaf(e0, L2E, Cr)) : 0.f;
            av0[j] = (bf16_t)(uni ? puni : p0);
            float x1 = f1r + f2s[kc1 + j];
            float e1 = fmaxf(x1, ALPHA * x1);
            float p1 = ((bits1 >> j) & 1u) ? exp2f(__builtin_fmaf(e1, L2E, Cr)) : 0.f;
            av1[j] = (bf16_t)(uni ? puni : p1);
        }
        #pragma unroll
        for (int t = 0; t < 4; ++t)
            acc[t] = __builtin_amdgcn_mfma_f32_16x16x32_bf16(av0, bv[t], acc[t], 0, 0, 0);
        #pragma unroll
        for (int t = 0; t < 4; ++t)
            acc[t] = __builtin_amdgcn_mfma_f32_16x16x32_bf16(av1, bv[4 + t], acc[t], 0, 0, 0);
    }

    float* outBase = outP + ((size_t)blockIdx.z * 2 + l) * (N_NODES * DH2);
    #pragma unroll
    for (int t = 0; t < 4; ++t) {
        const int col = t * 16 + l16;
        #pragma unroll
        for (int rr = 0; rr < 4; ++rr) {
            const int row = rowBase + wave * 16 + quad * 4 + rr;
            outBase[(size_t)row * DH2 + col] = acc[t][rr];
        }
    }
}

// ---------------------------------------------------------------- reduce K-split partials -> bf16 (layer 0)
__global__ __launch_bounds__(256) void reduce_kernel(
    const float* __restrict__ p, bf16_t* __restrict__ out, int n4, int S)
{
    int i = blockIdx.x * 256 + threadIdx.x;
    if (i >= n4) return;
    float4 a = ((const float4*)p)[i];
    for (int s = 1; s < S; ++s) {
        float4 b = ((const float4*)p)[(size_t)s * n4 + i];
        a.x += b.x; a.y += b.y; a.z += b.z; a.w += b.w;
    }
    bf16_t o[4] = {(bf16_t)a.x, (bf16_t)a.y, (bf16_t)a.z, (bf16_t)a.w};
    *(uint2*)(out + (size_t)i * 4) = *(const uint2*)o;
}

// ---------------------------------------------------------------- reduce L1/L2 partials + Z + hi/lo split
__global__ __launch_bounds__(256) void reduce_z_kernel(
    const float* __restrict__ part, const float* __restrict__ noise,
    bf16_t* __restrict__ ZA, bf16_t* __restrict__ ZB)
{
    const int idx = blockIdx.x * 256 + threadIdx.x;
    const int stride = 2 * N_NODES * DH2;
    float mean = 0.f, ls = 0.f;
    #pragma unroll
    for (int s = 0; s < 8; ++s) {
        mean += part[(size_t)s * stride + idx];
        ls   += part[(size_t)s * stride + N_NODES * DH2 + idx];
    }
    float z = noise[idx] * __expf(ls) + mean;
    bf16_t zhi = (bf16_t)z;
    bf16_t zlo = (bf16_t)(z - (float)zhi);
    const int i = idx >> 6, c = idx & 63;
    const size_t rb = (size_t)i * 256;
    ZA[rb + c]       = zhi;
    ZA[rb + 64 + c]  = zhi;
    ZA[rb + 128 + c] = zlo;
    ZA[rb + 192 + c] = zlo;
    ZB[rb + c]       = zhi;
    ZB[rb + 64 + c]  = zlo;
    ZB[rb + 128 + c] = zhi;
    ZB[rb + 192 + c] = zlo;
}

// ---------------------------------------------------------------- LDS-free GEMM (dense layers), k-unroll x2 batched
template <int WT>
__global__ __launch_bounds__(256) void gemm_bt_kernel(
    const bf16_t* __restrict__ A, const bf16_t* __restrict__ BT,
    bf16_t* __restrict__ C, bf16_t* __restrict__ Ct, int M, int N, int K)
{
    const int tid = threadIdx.x;
    const int wave = tid >> 6, lane = tid & 63, quad = lane >> 4, l16 = lane & 15;
    const int colBase = blockIdx.x * 64, rowBase = blockIdx.y * 64;
    const int mr = rowBase + wave * 16 + l16;
    const bf16_t* Ap = A + (size_t)mr * K + quad * 8;
    const bf16_t* Bp = BT + (size_t)(colBase + l16) * K + quad * 8;

    f32x4 acc[4] = {};
    for (int k0 = 0; k0 < K; k0 += 64) {
        bf16x8 bv[8];
        #pragma unroll
        for (int t = 0; t < 4; ++t) {
            bv[t]     = *(const bf16x8*)(Bp + (size_t)t * 16 * K + k0);
            bv[4 + t] = *(const bf16x8*)(Bp + (size_t)t * 16 * K + k0 + 32);
        }
        bf16x8 av0 = *(const bf16x8*)(Ap + k0);
        bf16x8 av1 = *(const bf16x8*)(Ap + k0 + 32);
        #pragma unroll
        for (int t = 0; t < 4; ++t)
            acc[t] = __builtin_amdgcn_mfma_f32_16x16x32_bf16(av0, bv[t], acc[t], 0, 0, 0);
        #pragma unroll
        for (int t = 0; t < 4; ++t)
            acc[t] = __builtin_amdgcn_mfma_f32_16x16x32_bf16(av1, bv[4 + t], acc[t], 0, 0, 0);
    }
    #pragma unroll
    for (int t = 0; t < 4; ++t) {
        const int col = colBase + t * 16 + l16;
        bf16_t pk[4];
        #pragma unroll
        for (int rr = 0; rr < 4; ++rr) {
            float v = acc[t][rr];
            const int row = rowBase + wave * 16 + quad * 4 + rr;
            C[(size_t)row * N + col] = (bf16_t)v;
            pk[rr] = (bf16_t)v;
        }
        if (WT) {
            *(uint2*)(Ct + (size_t)col * M + rowBase + wave * 16 + quad * 4) = *(const uint2*)pk;
        }
    }
}

// ---------------------------------------------------------------- final: sigmoid(ZA @ ZB^T), 64x256 tile, batched loads
template <int NT>
__global__ __launch_bounds__(256) void zzt_sigmoid_kernel(
    const bf16_t* __restrict__ ZA, const bf16_t* __restrict__ ZB, float* __restrict__ C)
{
    const int tid = threadIdx.x;
    const int wave = tid >> 6, lane = tid & 63, quad = lane >> 4, l16 = lane & 15;
    const int colBase = blockIdx.x * (NT * 16), rowBase = blockIdx.y * 64;
    const int mr = rowBase + wave * 16 + l16;
    const bf16_t* Ap = ZA + (size_t)mr * 256 + quad * 8;
    const bf16_t* Bp = ZB + (size_t)(colBase + l16) * 256 + quad * 8;

    f32x4 acc[NT] = {};
    for (int k0 = 0; k0 < 256; k0 += 32) {
        bf16x8 bv[NT];
        #pragma unroll
        for (int t = 0; t < NT; ++t)
            bv[t] = *(const bf16x8*)(Bp + (size_t)t * 16 * 256 + k0);
        bf16x8 av = *(const bf16x8*)(Ap + k0);
        #pragma unroll
        for (int t = 0; t < NT; ++t)
            acc[t] = __builtin_amdgcn_mfma_f32_16x16x32_bf16(av, bv[t], acc[t], 0, 0, 0);
    }
    #pragma unroll
    for (int t = 0; t < NT; ++t) {
        const int col = colBase + t * 16 + l16;
        #pragma unroll
        for (int rr = 0; rr < 4; ++rr) {
            const int row = rowBase + wave * 16 + quad * 4 + rr;
            float x = acc[t][rr];
            float v = __builtin_amdgcn_rcpf(1.0f + exp2f(-x * L2E));
            C[(size_t)row * N_NODES + col] = v;
        }
    }
}

// ================================================================ launch
extern "C" void kernel_launch(void* const* d_in, const int* in_sizes, int n_in,
                              void* d_out, int out_size, void* d_ws, size_t ws_size,
                              hipStream_t stream)
{
    const float* X     = (const float*)d_in[0];
    const int*   adj   = (const int*)  d_in[1];
    const float* noise = (const float*)d_in[2];
    const float* W0    = (const float*)d_in[3];
    const float* a0    = (const float*)d_in[4];
    const float* W1    = (const float*)d_in[5];
    const float* a1    = (const float*)d_in[6];
    const float* W2    = (const float*)d_in[7];
    const float* a2    = (const float*)d_in[8];
    float* out = (float*)d_out;

    char* ws = (char*)d_ws;
    size_t off = 0;
    auto alloc = [&](size_t bytes) { char* p = ws + off; off += (bytes + 255) & ~(size_t)255; return p; };

    unsigned long long* mask = (unsigned long long*)alloc((size_t)NWORDS * 8);    // 2 MB
    float*  part  = (float*)alloc((size_t)8 * N_NODES * DH1 * 4);                 // 32 MB
    bf16_t* Xb    = (bf16_t*)alloc((size_t)N_NODES * DIM_IN * 2);                 // 4 MB
    bf16_t* W0T   = (bf16_t*)alloc((size_t)DH1 * DIM_IN * 2);
    bf16_t* W12T  = (bf16_t*)alloc((size_t)128 * DH1 * 2);
    bf16_t* h0b   = (bf16_t*)alloc((size_t)N_NODES * DH1 * 2);                    // 2 MB
    bf16_t* h0T   = (bf16_t*)alloc((size_t)DH1 * N_NODES * 2);                    // 2 MB
    bf16_t* hidb  = (bf16_t*)alloc((size_t)N_NODES * DH1 * 2);                    // 2 MB
    bf16_t* h12b  = (bf16_t*)alloc((size_t)N_NODES * 128 * 2);                    // 1 MB
    bf16_t* h12T  = (bf16_t*)alloc((size_t)128 * N_NODES * 2);                    // 1 MB
    bf16_t* ZA    = (bf16_t*)alloc((size_t)N_NODES * 256 * 2);                    // 2 MB
    bf16_t* ZB    = (bf16_t*)alloc((size_t)N_NODES * 256 * 2);                    // 2 MB
    float* f1b  = (float*)alloc((size_t)2 * N_NODES * 4);
    float* f2b  = (float*)alloc((size_t)2 * N_NODES * 4);
    float* mrowb = (float*)alloc((size_t)2 * N_NODES * 4);
    float* srowb = (float*)alloc((size_t)2 * N_NODES * 4);
    (void)ws_size; (void)in_sizes; (void)n_in; (void)out_size;

    dim3 blk(256);

    // input conversions + mask pack
    cvt_kernel<<<(N_NODES * DIM_IN / 4 + 255) / 256, blk, 0, stream>>>(X, Xb, N_NODES * DIM_IN / 4);
    cvtT_kernel<<<(DH1 * DIM_IN + 255) / 256, blk, 0, stream>>>(W0, W0T, DH1, DIM_IN);
    w12t_kernel<<<(128 * DH1 + 255) / 256, blk, 0, stream>>>(W1, W2, W12T);
    pack_mask_kernel<<<2048, blk, 0, stream>>>(adj, mask);

    // ---- layer 0: hid = P0 @ (X@W0)
    gemm_bt_kernel<1><<<dim3(DH1 / 64, N_NODES / 64), blk, 0, stream>>>(
        Xb, W0T, h0b, h0T, N_NODES, DH1, DIM_IN);
    f1f2_kernel<<<N_NODES / 4, blk, 0, stream>>>(h0b, a0, f1b, f2b, DH1, DH1);
    rowstats_kernel<<<dim3(N_NODES / 4, 1), blk, 0, stream>>>(mask, f1b, f2b, mrowb, srowb);
    attn_fused_kernel<8, 512><<<dim3(2, N_NODES / 64, 8), blk, 0, stream>>>(
        mask, f1b, f2b, mrowb, srowb, h0T, part, DH1);
    reduce_kernel<<<(N_NODES * DH1 / 4 + 255) / 256, blk, 0, stream>>>(
        part, hidb, N_NODES * DH1 / 4, 8);

    // ---- h1|h2 = hid @ [W1|W2]
    gemm_bt_kernel<1><<<dim3(2, N_NODES / 64), blk, 0, stream>>>(
        hidb, W12T, h12b, h12T, N_NODES, 128, DH1);

    // ---- layers 1&2 merged: mean / logstd
    f1f2_dual_kernel<<<dim3(N_NODES / 4, 2), blk, 0, stream>>>(h12b, a1, a2, f1b, f2b);
    rowstats_kernel<<<dim3(N_NODES / 4, 2), blk, 0, stream>>>(mask, f1b, f2b, mrowb, srowb);
    attn12_kernel<512><<<dim3(2, N_NODES / 64, 8), blk, 0, stream>>>(
        mask, f1b, f2b, mrowb, srowb, h12T, part);
    reduce_z_kernel<<<(N_NODES * DH2) / 256, blk, 0, stream>>>(part, noise, ZA, ZB);

    // ---- A_pred = sigmoid(Z @ Z^T), K=256 exact hi/lo
    zzt_sigmoid_kernel<16><<<dim3(N_NODES / 256, N_NODES / 64), blk, 0, stream>>>(ZA, ZB, out);
}